// Round 4
// baseline (947.786 us; speedup 1.0000x reference)
//
#include <hip/hip_runtime.h>
#include <math.h>
#include <stdint.h>

typedef unsigned short u16;
typedef unsigned long long u64;
typedef __attribute__((ext_vector_type(8))) short bf16x8;
typedef __attribute__((ext_vector_type(4))) float f32x4;

__device__ __forceinline__ u16 bfhi(float v) {
  unsigned u = __float_as_uint(v);
  u += 0x7FFFu + ((u >> 16) & 1u);
  return (u16)(u >> 16);
}
__device__ __forceinline__ float b2f(u16 h) { return __uint_as_float((unsigned)h << 16); }

__device__ __forceinline__ void gload16(void* lds, const void* g) {
  __builtin_amdgcn_global_load_lds(
      (const __attribute__((address_space(1))) unsigned int*)g,
      (__attribute__((address_space(3))) unsigned int*)lds, 16, 0, 0);
}

// exact-erf GELU via Abramowitz-Stegun 7.1.26 (|erf err| <= 1.5e-7, branch-free)
// ~16 VALU vs ~50 for libm erff (which runs both divergent branches per wave).
__device__ __forceinline__ float gelu_erf(float x) {
  const float z = fabsf(x) * 0.70710678118654752f;
  const float t = __builtin_amdgcn_rcpf(fmaf(0.3275911f, z, 1.0f));
  float p = fmaf(1.061405429f, t, -1.453152027f);
  p = fmaf(p, t, 1.421413741f);
  p = fmaf(p, t, -0.284496736f);
  p = fmaf(p, t, 0.254829592f);
  p *= t;
  const float E = p * __expf(-z * z);  // erfc(z), z >= 0 (no cancellation)
  const float hxE = 0.5f * x * E;
  return x >= 0.f ? x - hxE : hxE;
}

// ---------- depthwise conv 7x7 + bias: NCHW -> NCHW (coalesced float4 stores) ----------
// LDS: 70 rows x pitch 76, center at col' = w + 4 + 4*((row>>2)&1)  (bank-ideal reads)
__global__ __launch_bounds__(256) void k_conv(const float* __restrict__ in,
                                              const float* __restrict__ cw,
                                              const float* __restrict__ cb,
                                              float* __restrict__ out) {
  const int bx = blockIdx.x;  // 8b x 256c
  const int c = bx & 255;
  __shared__ float patch[70 * 76];
  const int t = threadIdx.x;
  const float* plane = in + (size_t)bx * 4096;
  // stage 1330 float4 chunks (19 per row)
  for (int i = t; i < 1330; i += 256) {
    const int row = i / 19, cf = i - row * 19;
    const int bit = (row >> 2) & 1;
    const int gf = cf - 1 - bit;  // global float4 index
    const int h = row - 3;
    float4 v = {0.f, 0.f, 0.f, 0.f};
    if ((unsigned)h < 64u && (unsigned)gf < 16u) v = *(const float4*)(plane + h * 64 + gf * 4);
    *(float4*)(patch + row * 76 + cf * 4) = v;
  }
  const float* wp = cw + c * 49;  // block-uniform -> SGPR loads
  float wt[49];
#pragma unroll
  for (int i = 0; i < 49; ++i) wt[i] = wp[i];
  const float bias = cb[c];
  __syncthreads();
  const int j = t & 7, i = t >> 3;  // w0 = 8j, output rows 2i, 2i+1
  const int w0 = j * 8, h0 = i * 2;
  float acc[2][8];
#pragma unroll
  for (int dr = 0; dr < 2; ++dr)
#pragma unroll
    for (int ww = 0; ww < 8; ++ww) acc[dr][ww] = bias;
#pragma unroll
  for (int r = 0; r < 8; ++r) {  // patch rows h0 .. h0+7 (global h0-3 .. h0+4)
    const int prow = h0 + r;
    const int bit = (prow >> 2) & 1;
    const float* base = patch + prow * 76 + w0 + 4 * bit;
    float win[16];
#pragma unroll
    for (int q = 0; q < 4; ++q) {
      const float4 v = *(const float4*)(base + q * 4);
      win[q * 4 + 0] = v.x; win[q * 4 + 1] = v.y;
      win[q * 4 + 2] = v.z; win[q * 4 + 3] = v.w;
    }
#pragma unroll
    for (int dr = 0; dr < 2; ++dr) {
      const int kh = r - dr;
      if (kh >= 0 && kh < 7) {
#pragma unroll
        for (int kw = 0; kw < 7; ++kw) {
          const float wv = wt[kh * 7 + kw];
#pragma unroll
          for (int ww = 0; ww < 8; ++ww)
            acc[dr][ww] = fmaf(win[ww + kw + 1], wv, acc[dr][ww]);
        }
      }
    }
  }
  float* op = out + (size_t)bx * 4096;
#pragma unroll
  for (int dr = 0; dr < 2; ++dr) {
    const int hh = h0 + dr;
    float4 o1, o2;
    o1.x = acc[dr][0]; o1.y = acc[dr][1]; o1.z = acc[dr][2]; o1.w = acc[dr][3];
    o2.x = acc[dr][4]; o2.y = acc[dr][5]; o2.z = acc[dr][6]; o2.w = acc[dr][7];
    *(float4*)(op + hh * 64 + w0) = o1;
    *(float4*)(op + hh * 64 + w0 + 4) = o2;
  }
}

// ---------- LN over channels from NCHW, via LDS transpose -> NHWC bf16 hi/lo ----------
// 32 px per block; T[c][p] pitch 33
__global__ __launch_bounds__(256) void k_lnT(const float* __restrict__ src,
                                             const float* __restrict__ g,
                                             const float* __restrict__ bt,
                                             u16* __restrict__ Rh, u16* __restrict__ Rl,
                                             const int wlo) {
  __shared__ float T[256 * 33];
  __shared__ float red[8 * 32];
  __shared__ float gs[256], bs[256];
  const int t = threadIdx.x;
  const int n0 = blockIdx.x * 32;
  const int b = n0 >> 12, pl = n0 & 4095;
  gs[t] = g[t];
  bs[t] = bt[t];
  const int m = t & 7, h = t >> 3;  // m: px quad, h: channel-in-group
  const float* sp = src + (((size_t)(b * 256)) << 12) + pl + m * 4;
#pragma unroll
  for (int it = 0; it < 8; ++it) {
    const int c = it * 32 + h;
    const float4 v = *(const float4*)(sp + ((size_t)c << 12));
    *(float4*)(T + c * 33 + m * 4) = v;
  }
  __syncthreads();
  const int p = t & 31, qq = t >> 5;
  float s = 0.f;
#pragma unroll
  for (int jj = 0; jj < 32; ++jj) s += T[(qq * 32 + jj) * 33 + p];
  red[qq * 32 + p] = s;
  __syncthreads();
  float tot = 0.f;
#pragma unroll
  for (int k = 0; k < 8; ++k) tot += red[k * 32 + p];
  const float mu = tot * (1.0f / 256.0f);
  __syncthreads();
  float s2 = 0.f;
#pragma unroll
  for (int jj = 0; jj < 32; ++jj) {
    const float d = T[(qq * 32 + jj) * 33 + p] - mu;
    s2 = fmaf(d, d, s2);
  }
  red[qq * 32 + p] = s2;
  __syncthreads();
  float tot2 = 0.f;
#pragma unroll
  for (int k = 0; k < 8; ++k) tot2 += red[k * 32 + p];
  const float rs = 1.0f / sqrtf(tot2 * (1.0f / 256.0f) + 1e-5f);
#pragma unroll
  for (int jj = 0; jj < 32; ++jj) {
    const int c = qq * 32 + jj;
    const float y = (T[c * 33 + p] - mu) * rs * gs[c] + bs[c];
    const u16 hh = bfhi(y);
    const u16 ll = bfhi(y - b2f(hh));
    ((unsigned*)T)[c * 33 + p] = ((unsigned)hh << 16) | ll;
  }
  __syncthreads();
  const int w = t >> 6, l = t & 63;
  const unsigned* Tu = (const unsigned*)T;
#pragma unroll
  for (int r = 0; r < 4; ++r) {
    const int px = r * 8 + w * 2 + (l >> 5);
    const int c0 = (l & 31) * 8;
    unsigned hp[4], lp[4];
#pragma unroll
    for (int jj = 0; jj < 4; ++jj) {
      const unsigned a = Tu[(c0 + 2 * jj) * 33 + px];
      const unsigned bb = Tu[(c0 + 2 * jj + 1) * 33 + px];
      hp[jj] = (a >> 16) | (bb & 0xffff0000u);
      lp[jj] = (a & 0xffffu) | (bb << 16);
    }
    const size_t base = (size_t)(n0 + px) * 256 + c0;
    *(uint4*)(Rh + base) = make_uint4(hp[0], hp[1], hp[2], hp[3]);
    if (wlo) *(uint4*)(Rl + base) = make_uint4(lp[0], lp[1], lp[2], lp[3]);
  }
}

// ---------- fused-term MFMA GEMM: C = (Ah+Al) * (Bh+Bl)^T (drop lo*lo) ----------
// 2-phase double-buffered pipeline, BK=32 (the verified minimum-2-phase schedule):
//   per iter: ds_read(cur) -> issue gload(next) -> sched_barrier -> MFMA -> __syncthreads.
// LDS swizzle: slot = ((row>>1)&3)^quad over 64B rows (period 8, conflict-free, HW-verified).
// Block id remap: XCD = rowt%8, colt fastest in dispatch order -> A-tile L2-resident.
// EPI 0: fc1 (+bias, GELU, split->Mh/Ml, GRN sumsq atomics)
// EPI 1: fc2 (+bias, +xin NCHW residual via LDS transpose; xout NCHW and/or Eh/El rows)
// EPI 2: vq  (d2 = (tn - 2a) + c2, packed u64 atomicMin per row)
template <int KD, int SPLIT, int EPI, int NCT>
__global__ __launch_bounds__(256) void k_gemm(
    const u16* __restrict__ Ah_, const u16* __restrict__ Al_,
    const u16* __restrict__ Bh_, const u16* __restrict__ Bl_,
    const int row0, const long long bstride,
    const float* __restrict__ pbias,
    u16* __restrict__ poh, u16* __restrict__ pol,
    float* __restrict__ pxout, const float* __restrict__ pxin,
    float* __restrict__ pgx2, u64* __restrict__ pmin) {
  constexpr int HALF_B = (SPLIT ? 4 : 2) * 8192;  // bytes per pipeline buffer
  constexpr int STAGE_B = 2 * HALF_B;
  constexpr int TRANS_B = (EPI == 1) ? 64 * 129 * 4 : 0;
  constexpr int SMEM_B = STAGE_B > TRANS_B ? STAGE_B : TRANS_B;
  constexpr int NS = KD / 32;
  __shared__ __align__(16) char smem[SMEM_B];

  const int t = threadIdx.x;
  const int w = t >> 6, l = t & 63;
  const int quad = l >> 4, lm = l & 15;
  const int wr = (w & 1) * 64, wc = (w >> 1) * 64;
  // linear block id -> (rowt, colt): colt fastest among dispatch, XCD(id%8)=rowt%8
  const int id = blockIdx.x + gridDim.x * blockIdx.y;
  constexpr int L = (NCT == 8) ? 3 : 1;
  const int colt = (id >> 3) & (NCT - 1);
  const int rowt = (id & 7) + ((id >> (3 + L)) << 3);
  const int nblk0 = rowt * 128;
  const int bglob = (row0 + nblk0) >> 12;

  const u16* Agh = Ah_ + (size_t)nblk0 * KD;
  const u16* Agl = SPLIT ? (Al_ + (size_t)nblk0 * KD) : Ah_;
  const u16* Bgh = Bh_ + (size_t)bglob * (size_t)bstride + (size_t)(colt * 128) * KD;
  const u16* Bgl = SPLIT ? (Bl_ + (size_t)bglob * (size_t)bstride + (size_t)(colt * 128) * KD) : Bh_;

  f32x4 acc[4][4];
  const f32x4 zz = {0.f, 0.f, 0.f, 0.f};
#pragma unroll
  for (int i = 0; i < 4; ++i)
#pragma unroll
    for (int j = 0; j < 4; ++j) acc[i][j] = zz;

  // stage one 8KB slab (128 rows x 32 K bf16); LDS dest linear, source pre-swizzled
  auto stage32 = [&](char* Sp, const u16* Gp, int ks) {
#pragma unroll
    for (int ii = 0; ii < 2; ++ii) {
      const int o = ii * 4096 + t * 16;                // byte offset in slab
      const int row = o >> 6;                          // 64B per row
      const int lc = ((o >> 4) & 3) ^ ((row >> 1) & 3);  // logical 16B chunk
      gload16(Sp + o, Gp + (size_t)row * KD + ks * 32 + lc * 8);
    }
  };
  auto stage_all = [&](int b, int ks) {
    char* base = smem + (size_t)b * HALF_B;
    stage32(base, Agh, ks);
    stage32(base + 8192, Bgh, ks);
    if constexpr (SPLIT) {
      stage32(base + 16384, Agl, ks);
      stage32(base + 24576, Bgl, ks);
    }
  };
  // swizzled fragment read: row rc, logical K-chunk = quad
  auto frag_at = [&](const u16* S, int rc) -> bf16x8 {
    const int sw = ((rc >> 1) & 3) ^ quad;
    return *(const bf16x8*)(S + rc * 32 + (sw << 3));
  };

  stage_all(0, 0);
  __syncthreads();

#pragma unroll 1
  for (int ks = 0; ks < NS; ++ks) {
    const u16* base = (const u16*)(smem + (size_t)(ks & 1) * HALF_B);
    bf16x8 ah[4], bh[4], al[4], bl[4];
#pragma unroll
    for (int i = 0; i < 4; ++i) {
      ah[i] = frag_at(base, wr + i * 16 + lm);
      bh[i] = frag_at(base + 4096, wc + i * 16 + lm);
    }
    if constexpr (SPLIT) {
#pragma unroll
      for (int i = 0; i < 4; ++i) {
        al[i] = frag_at(base + 8192, wr + i * 16 + lm);
        bl[i] = frag_at(base + 12288, wc + i * 16 + lm);
      }
    }
    // issue next-tile prefetch while this tile's MFMAs run
    if (ks + 1 < NS) stage_all((ks + 1) & 1, ks + 1);
    __builtin_amdgcn_sched_barrier(0);  // keep gloads above the MFMA cluster
#pragma unroll
    for (int i = 0; i < 4; ++i)
#pragma unroll
      for (int j = 0; j < 4; ++j)
        acc[i][j] = __builtin_amdgcn_mfma_f32_16x16x32_bf16(ah[i], bh[j], acc[i][j], 0, 0, 0);
    if constexpr (SPLIT) {
#pragma unroll
      for (int i = 0; i < 4; ++i)
#pragma unroll
        for (int j = 0; j < 4; ++j)
          acc[i][j] = __builtin_amdgcn_mfma_f32_16x16x32_bf16(al[i], bh[j], acc[i][j], 0, 0, 0);
#pragma unroll
      for (int i = 0; i < 4; ++i)
#pragma unroll
        for (int j = 0; j < 4; ++j)
          acc[i][j] = __builtin_amdgcn_mfma_f32_16x16x32_bf16(ah[i], bl[j], acc[i][j], 0, 0, 0);
    }
    __syncthreads();  // vmcnt(0)+lgkmcnt(0) drain: prefetch lands, buffer handoff
  }

  if constexpr (EPI == 0) {
    float csum[4] = {0.f, 0.f, 0.f, 0.f};
    float bv[4];
#pragma unroll
    for (int j = 0; j < 4; ++j) bv[j] = pbias[colt * 128 + wc + j * 16 + lm];
#pragma unroll
    for (int i = 0; i < 4; ++i) {
#pragma unroll
      for (int r = 0; r < 4; ++r) {
        const int row = nblk0 + wr + i * 16 + quad * 4 + r;
#pragma unroll
        for (int j = 0; j < 4; ++j) {
          const int col = colt * 128 + wc + j * 16 + lm;
          const float x = acc[i][j][r] + bv[j];
          const float gl = gelu_erf(x);
          csum[j] = fmaf(gl, gl, csum[j]);
          const size_t idx = (size_t)row * 1024 + col;
          const u16 h = bfhi(gl);
          poh[idx] = h;
          if constexpr (SPLIT) pol[idx] = bfhi(gl - b2f(h));
        }
      }
    }
#pragma unroll
    for (int j = 0; j < 4; ++j) {
      float cs = csum[j];
      cs += __shfl_xor(cs, 16);
      cs += __shfl_xor(cs, 32);
      if (quad == 0)
        unsafeAtomicAdd(&pgx2[bglob * 1024 + colt * 128 + wc + j * 16 + lm], cs);
    }
  } else if constexpr (EPI == 1) {
    float* T = (float*)smem;  // [64 cols][pitch 129] f32, per col-half
    const int pg0 = (row0 + nblk0) & 4095;
    const int bb = (row0 + nblk0) >> 12;
#pragma unroll 1
    for (int h = 0; h < 2; ++h) {
      __syncthreads();
      if ((w >> 1) == h) {
#pragma unroll
        for (int i = 0; i < 4; ++i) {
          const int row = wr + i * 16 + quad * 4;
#pragma unroll
          for (int j = 0; j < 4; ++j) {
            const int cl = j * 16 + lm;
#pragma unroll
            for (int r = 0; r < 4; ++r) T[cl * 129 + row + r] = acc[i][j][r];
          }
        }
      }
      __syncthreads();
      const int lp = (l & 31) * 4;
      const int ch2 = l >> 5;
#pragma unroll
      for (int step = 0; step < 8; ++step) {
        const int cl = w * 16 + step * 2 + ch2;
        const int cg = colt * 128 + h * 64 + cl;
        float4 tv = *(float4*)&T[cl * 129 + lp];
        const float bv2 = pbias[cg];
        const size_t nchw = (((size_t)(bb * 256 + cg)) << 12) + pg0 + lp;
        const float4 xv = *(const float4*)(pxin + nchw);
        float4 z;
        z.x = tv.x + bv2 + xv.x;
        z.y = tv.y + bv2 + xv.y;
        z.z = tv.z + bv2 + xv.z;
        z.w = tv.w + bv2 + xv.w;
        if (pxout) *(float4*)(pxout + nchw) = z;
        if (poh) *(float4*)&T[cl * 129 + lp] = z;
      }
      if (poh) {
        __syncthreads();
        const int cl3 = t & 63;
        const int cg3 = colt * 128 + h * 64 + cl3;
        const int r0 = (t >> 6) * 32;
#pragma unroll
        for (int n = 0; n < 32; ++n) {
          const float z = T[cl3 * 129 + r0 + n];
          const size_t idx = (size_t)(nblk0 + r0 + n) * 256 + cg3;
          const u16 hh = bfhi(z);
          poh[idx] = hh;
          pol[idx] = bfhi(z - b2f(hh));
        }
      }
    }
  } else {
#pragma unroll
    for (int i = 0; i < 4; ++i) {
#pragma unroll
      for (int r = 0; r < 4; ++r) {
        const int nloc = nblk0 + wr + i * 16 + quad * 4 + r;
        const float tnv = pxin[nloc];
        u64 best = ~0ULL;
#pragma unroll
        for (int j = 0; j < 4; ++j) {
          const int code = colt * 128 + wc + j * 16 + lm;
          const float d = __fadd_rn(__fsub_rn(tnv, __fmul_rn(2.0f, acc[i][j][r])), pbias[code]);
          const u64 pk = (((u64)__float_as_uint(d)) << 32) | (unsigned)code;
          best = pk < best ? pk : best;
        }
#pragma unroll
        for (int off = 1; off < 16; off <<= 1) {
          unsigned lo32 = (unsigned)best, hi32 = (unsigned)(best >> 32);
          lo32 = __shfl_xor(lo32, off);
          hi32 = __shfl_xor(hi32, off);
          const u64 o2 = (((u64)hi32) << 32) | lo32;
          best = o2 < best ? o2 : best;
        }
        if (lm == 0) atomicMin(pmin + nloc, best);
      }
    }
  }
}

// ---------- row sumsq (tn) from bf16 hi/lo E rows ----------
__global__ __launch_bounds__(256) void k_rownorm(const u16* __restrict__ Eh,
                                                 const u16* __restrict__ El,
                                                 float* __restrict__ tn) {
  const int t = threadIdx.x;
  const int r = t >> 2, p = t & 3;
  const int n = blockIdx.x * 64 + r;
  const u16* ph = Eh + (size_t)n * 256 + p * 64;
  const u16* pl = El + (size_t)n * 256 + p * 64;
  float s = 0.f;
#pragma unroll
  for (int j = 0; j < 8; ++j) {
    const uint4 hv = *(const uint4*)(ph + j * 8);
    const uint4 lv = *(const uint4*)(pl + j * 8);
    const unsigned hu[4] = {hv.x, hv.y, hv.z, hv.w};
    const unsigned lu[4] = {lv.x, lv.y, lv.z, lv.w};
#pragma unroll
    for (int q = 0; q < 4; ++q) {
      const float v0 = b2f((u16)(hu[q] & 0xffff)) + b2f((u16)(lu[q] & 0xffff));
      const float v1 = b2f((u16)(hu[q] >> 16)) + b2f((u16)(lu[q] >> 16));
      s = fmaf(v0, v0, s);
      s = fmaf(v1, v1, s);
    }
  }
  s += __shfl_xor(s, 1);
  s += __shfl_xor(s, 2);
  if (p == 0) tn[n] = s;
}

// ---------- GRN scale s = 1 + gg*nx from sumsq ----------
__global__ __launch_bounds__(256) void k_grn_scale(const float* __restrict__ GX2,
                                                   const float* __restrict__ gg,
                                                   float* __restrict__ S, int b0) {
  const int b = b0 + blockIdx.x, t = threadIdx.x;
  const float* gxb = GX2 + (size_t)b * 1024;
  float gx[4];
  float s = 0.f;
#pragma unroll
  for (int i = 0; i < 4; ++i) {
    gx[i] = sqrtf(gxb[t + i * 256]);
    s += gx[i];
  }
  const int w = t >> 6, l = t & 63;
#pragma unroll
  for (int o = 32; o > 0; o >>= 1) s += __shfl_down(s, o);
  __shared__ float red[4];
  __shared__ float bc;
  if (l == 0) red[w] = s;
  __syncthreads();
  if (t == 0) bc = 1.0f / ((red[0] + red[1] + red[2] + red[3]) * (1.0f / 1024.0f) + 1e-6f);
  __syncthreads();
  const float inv = bc;
#pragma unroll
  for (int i = 0; i < 4; ++i)
    S[(size_t)b * 1024 + t + i * 256] = fmaf(gg[t + i * 256], gx[i] * inv, 1.0f);
}

// ---------- per-batch scaled+split+transposed W2 ----------
__global__ __launch_bounds__(256) void k_w2prep(const float* __restrict__ W2,
                                                const float* __restrict__ S, int b0,
                                                u16* __restrict__ Wh, u16* __restrict__ Wl) {
  const int bx = blockIdx.x;
  const int b = b0 + (bx >> 8), n = bx & 255;
  const int t = threadIdx.x;
#pragma unroll
  for (int j = 0; j < 4; ++j) {
    const int k = t + j * 256;
    const float v = W2[(size_t)k * 256 + n] * S[(size_t)b * 1024 + k];
    const size_t idx = ((size_t)(b * 256 + n)) * 1024 + k;
    const u16 h = bfhi(v);
    Wh[idx] = h;
    Wl[idx] = bfhi(v - b2f(h));
  }
}

// ---------- bias2v = b2 + gb @ W2 (one block per output channel) ----------
__global__ __launch_bounds__(256) void k_bias2(const float* __restrict__ W2,
                                               const float* __restrict__ gb,
                                               const float* __restrict__ b2,
                                               float* __restrict__ out) {
  const int c = blockIdx.x, t = threadIdx.x;
  float acc = 0.f;
#pragma unroll
  for (int j = 0; j < 4; ++j) {
    const int k = t + j * 256;
    acc = fmaf(gb[k], W2[(size_t)k * 256 + c], acc);
  }
  const int w = t >> 6, l = t & 63;
#pragma unroll
  for (int o = 32; o > 0; o >>= 1) acc += __shfl_down(acc, o);
  __shared__ float red[4];
  if (l == 0) red[w] = acc;
  __syncthreads();
  if (t == 0) out[c] = red[0] + red[1] + red[2] + red[3] + b2[c];
}

// ---------- W1^T split ----------
__global__ __launch_bounds__(256) void k_wt(const float* __restrict__ W1,
                                            u16* __restrict__ Wh, u16* __restrict__ Wl) {
  const int bx = blockIdx.x;  // d*1024 + n
  const int d = bx >> 10, n = bx & 1023;
  const int k = threadIdx.x;
  const float v = W1[(size_t)d * 262144 + (size_t)k * 1024 + n];
  const size_t idx = (size_t)bx * 256 + k;
  const u16 h = bfhi(v);
  Wh[idx] = h;
  Wl[idx] = bfhi(v - b2f(h));
}

// ---------- codebook split ----------
__global__ __launch_bounds__(256) void k_csplit(const float* __restrict__ C,
                                                u16* __restrict__ Ch, u16* __restrict__ Cl) {
  const size_t i = (size_t)blockIdx.x * 256 + threadIdx.x;
  const float v = C[i];
  const u16 h = bfhi(v);
  Ch[i] = h;
  Cl[i] = bfhi(v - b2f(h));
}

// ---------- numpy-pairwise |c|^2 per code ----------
__device__ __forceinline__ float np_pairwise_sq_256(const float* p) {
  float half[2];
#pragma unroll
  for (int hh = 0; hh < 2; ++hh) {
    float r[8];
#pragma unroll
    for (int j = 0; j < 8; ++j) {
      const float v = p[hh * 128 + j];
      r[j] = __fmul_rn(v, v);
    }
    for (int i = 8; i < 128; i += 8) {
#pragma unroll
      for (int j = 0; j < 8; ++j) {
        const float v = p[hh * 128 + i + j];
        r[j] = __fadd_rn(r[j], __fmul_rn(v, v));
      }
    }
    half[hh] = __fadd_rn(__fadd_rn(__fadd_rn(r[0], r[1]), __fadd_rn(r[2], r[3])),
                         __fadd_rn(__fadd_rn(r[4], r[5]), __fadd_rn(r[6], r[7])));
  }
  return __fadd_rn(half[0], half[1]);
}

__global__ __launch_bounds__(256) void k_c2(const float* __restrict__ cbk, float* __restrict__ c2) {
  const int k = blockIdx.x * 256 + threadIdx.x;
  c2[k] = np_pairwise_sq_256(cbk + (size_t)k * 256);
}

// ---------- index output + quantized gather ----------
__global__ __launch_bounds__(256) void k_idx(const u64* __restrict__ pk, float* __restrict__ outI) {
  const int n = blockIdx.x * 256 + threadIdx.x;
  outI[n] = (float)(unsigned)(pk[n] & 0xffffffffULL);
}

// 64 consecutive pixels per block; lanes = pixels so NCHW writes coalesce
__global__ __launch_bounds__(256) void k_gather(const u64* __restrict__ pk,
                                                const float* __restrict__ cbk,
                                                float* __restrict__ outq) {
  const int t = threadIdx.x;
  const int p0 = blockIdx.x * 64;
  const int b = p0 >> 12, pl = (p0 & 4095) + (t & 63);
  const int cg = t >> 6;  // 4 channel groups of 64
  const int n = p0 + (t & 63);
  const int k = (int)(unsigned)(pk[n] & 0xffffffffULL);
  const float* crow = cbk + (size_t)k * 256 + cg * 64;
  float* ob = outq + (((size_t)(b * 256 + cg * 64)) << 12) + pl;
#pragma unroll 1
  for (int j = 0; j < 16; ++j) {
    const float4 cv = *(const float4*)(crow + j * 4);
    ob[((size_t)(j * 4 + 0)) << 12] = cv.x;
    ob[((size_t)(j * 4 + 1)) << 12] = cv.y;
    ob[((size_t)(j * 4 + 2)) << 12] = cv.z;
    ob[((size_t)(j * 4 + 3)) << 12] = cv.w;
  }
}

extern "C" void kernel_launch(void* const* d_in, const int* in_sizes, int n_in,
                              void* d_out, int out_size, void* d_ws, size_t ws_size,
                              hipStream_t stream) {
  const float* x = (const float*)d_in[0];
  const float* cbk = (const float*)d_in[1];
  const float* Pe[10];
  const float* Pd[10];
  for (int i = 0; i < 10; ++i) Pe[i] = (const float*)d_in[2 + i];
  for (int i = 0; i < 10; ++i) Pd[i] = (const float*)d_in[12 + i];
  // order per dict: conv_w, conv_b, ln_g, ln_b, fc1_w, fc1_b, grn_g, grn_b, fc2_w, fc2_b

  float* ws = (float*)d_ws;
  size_t o = 0;
  auto alloc = [&](size_t nf) {
    float* p = ws + o;
    o += (nf + 63) & ~(size_t)63;
    return p;
  };
  float* P1 = alloc(8388608);      // NCHW ping
  u16* Rh = (u16*)alloc(4194304);  // rows hi (also E hi)
  u16* Rl = (u16*)alloc(4194304);  // rows lo (also E lo)
  u16* W1th_e = (u16*)alloc(262144);
  u16* W1tl_e = (u16*)alloc(262144);
  u16* W1th_d = (u16*)alloc(262144);
  u16* W1tl_d = (u16*)alloc(262144);
  u16* W2sh = (u16*)alloc(1048576);
  u16* W2sl = (u16*)alloc(1048576);
  u16* Ch = (u16*)alloc(131072);
  u16* Cl = (u16*)alloc(131072);
  float* C2v = alloc(1024);
  float* GX2 = alloc(8192);
  float* Sv = alloc(8192);
  float* bias2v = alloc(256);
  float* tn = alloc(32768);
  u64* pk = (u64*)alloc(65536);
  const size_t fixedf = o;
  const size_t availf = (ws_size / 4 > fixedf) ? ws_size / 4 - fixedf : 0;
  int chunkB = (int)(availf / 4194304);  // Mh+Ml per batch = 4M floats worth
  if (chunkB > 8) chunkB = 8;
  if (chunkB < 1) chunkB = 1;
  float* Cv = ws + o;  // conv NCHW fp32, aliases M arena (dead by fc1 time)
  u16* Mh = (u16*)(ws + o);
  u16* Ml = (u16*)(ws + o + (size_t)chunkB * 2097152);

  float* outQ = (float*)d_out;
  float* outD = outQ + 8388608;
  float* outI = outD + 8388608;

  auto run_enc = [&](const float* xin, float* xout, u16* Eh, u16* El,
                     const float* const* pp, int d) {
    k_conv<<<2048, 256, 0, stream>>>(xin, pp[0] + (size_t)d * 256 * 49, pp[1] + d * 256, Cv);
    k_lnT<<<1024, 256, 0, stream>>>(Cv, pp[2] + d * 256, pp[3] + d * 256, Rh, Rl, 1);
    k_bias2<<<256, 256, 0, stream>>>(pp[8] + (size_t)d * 262144, pp[7] + d * 1024,
                                     pp[9] + d * 256, bias2v);
    hipMemsetAsync(GX2, 0, 8192 * 4, stream);
    for (int b0 = 0; b0 < 8; b0 += chunkB) {
      const int nb = (8 - b0 < chunkB) ? 8 - b0 : chunkB;
      k_gemm<256, 1, 0, 8><<<dim3(8, nb * 32), 256, 0, stream>>>(
          Rh + (size_t)b0 * 4096 * 256, Rl + (size_t)b0 * 4096 * 256,
          W1th_e + (size_t)d * 262144, W1tl_e + (size_t)d * 262144,
          b0 * 4096, 0, Pe[5] + d * 1024, Mh, Ml, nullptr, nullptr, GX2, nullptr);
      k_grn_scale<<<nb, 256, 0, stream>>>(GX2, pp[6] + d * 1024, Sv, b0);
      k_w2prep<<<nb * 256, 256, 0, stream>>>(pp[8] + (size_t)d * 262144, Sv, b0, W2sh, W2sl);
      k_gemm<1024, 1, 1, 2><<<dim3(2, nb * 32), 256, 0, stream>>>(
          Mh, Ml, W2sh, W2sl, b0 * 4096, 262144LL, bias2v,
          Eh ? Eh + (size_t)b0 * 4096 * 256 : (u16*)nullptr,
          El ? El + (size_t)b0 * 4096 * 256 : (u16*)nullptr,
          xout, xin, nullptr, nullptr);
    }
  };

  auto run_dec = [&](const float* xin, float* xout, const float* const* pp, int d) {
    k_conv<<<2048, 256, 0, stream>>>(xin, pp[0] + (size_t)d * 256 * 49, pp[1] + d * 256, Cv);
    k_lnT<<<1024, 256, 0, stream>>>(Cv, pp[2] + d * 256, pp[3] + d * 256, Rh, Rl, 0);
    k_bias2<<<256, 256, 0, stream>>>(pp[8] + (size_t)d * 262144, pp[7] + d * 1024,
                                     pp[9] + d * 256, bias2v);
    hipMemsetAsync(GX2, 0, 8192 * 4, stream);
    for (int b0 = 0; b0 < 8; b0 += chunkB) {
      const int nb = (8 - b0 < chunkB) ? 8 - b0 : chunkB;
      k_gemm<256, 0, 0, 8><<<dim3(8, nb * 32), 256, 0, stream>>>(
          Rh + (size_t)b0 * 4096 * 256, nullptr,
          W1th_d + (size_t)d * 262144, nullptr,
          b0 * 4096, 0, Pd[5] + d * 1024, Mh, nullptr, nullptr, nullptr, GX2, nullptr);
      k_grn_scale<<<nb, 256, 0, stream>>>(GX2, pp[6] + d * 1024, Sv, b0);
      k_w2prep<<<nb * 256, 256, 0, stream>>>(pp[8] + (size_t)d * 262144, Sv, b0, W2sh, W2sl);
      k_gemm<1024, 0, 1, 2><<<dim3(2, nb * 32), 256, 0, stream>>>(
          Mh, nullptr, W2sh, nullptr, b0 * 4096, 262144LL, bias2v,
          nullptr, nullptr, xout, xin, nullptr, nullptr);
    }
  };

  // prep
  k_wt<<<2048, 256, 0, stream>>>(Pe[4], W1th_e, W1tl_e);
  k_wt<<<2048, 256, 0, stream>>>(Pd[4], W1th_d, W1tl_d);
  k_csplit<<<1024, 256, 0, stream>>>(cbk, Ch, Cl);
  k_c2<<<4, 256, 0, stream>>>(cbk, C2v);

  // encoder (split-bf16, fused 3-term)
  run_enc(x, P1, nullptr, nullptr, Pe, 0);
  run_enc(P1, nullptr, Rh, Rl, Pe, 1);  // E -> Rh/Rl, no NCHW out

  // VQ
  k_rownorm<<<512, 256, 0, stream>>>(Rh, Rl, tn);
  hipMemsetAsync(pk, 0xFF, 32768 * 8, stream);
  k_gemm<256, 1, 2, 8><<<dim3(8, 256), 256, 0, stream>>>(Rh, Rl, Ch, Cl, 0, 0,
                                                         C2v, nullptr, nullptr, nullptr,
                                                         tn, nullptr, pk);
  k_idx<<<128, 256, 0, stream>>>(pk, outI);
  k_gather<<<512, 256, 0, stream>>>(pk, cbk, outQ);

  // decoder (plain bf16)
  run_dec(outQ, P1, Pd, 0);
  run_dec(P1, outD, Pd, 1);
}

// Round 5
// 890.244 us; speedup vs baseline: 1.0646x; 1.0646x over previous
//
#include <hip/hip_runtime.h>
#include <math.h>
#include <stdint.h>

typedef unsigned short u16;
typedef unsigned long long u64;
typedef __attribute__((ext_vector_type(8))) short bf16x8;
typedef __attribute__((ext_vector_type(4))) float f32x4;

__device__ __forceinline__ u16 bfhi(float v) {
  unsigned u = __float_as_uint(v);
  u += 0x7FFFu + ((u >> 16) & 1u);
  return (u16)(u >> 16);
}
__device__ __forceinline__ float b2f(u16 h) { return __uint_as_float((unsigned)h << 16); }

__device__ __forceinline__ void gload16(void* lds, const void* g) {
  __builtin_amdgcn_global_load_lds(
      (const __attribute__((address_space(1))) unsigned int*)g,
      (__attribute__((address_space(3))) unsigned int*)lds, 16, 0, 0);
}

// ---------- depthwise conv 7x7 + bias: NCHW -> NCHW (coalesced float4 stores) ----------
// LDS: 70 rows x pitch 76, center at col' = w + 4 + 4*((row>>2)&1)  (bank-ideal reads)
__global__ __launch_bounds__(256) void k_conv(const float* __restrict__ in,
                                              const float* __restrict__ cw,
                                              const float* __restrict__ cb,
                                              float* __restrict__ out) {
  const int bx = blockIdx.x;  // 8b x 256c
  const int c = bx & 255;
  __shared__ float patch[70 * 76];
  const int t = threadIdx.x;
  const float* plane = in + (size_t)bx * 4096;
  // stage 1330 float4 chunks (19 per row)
  for (int i = t; i < 1330; i += 256) {
    const int row = i / 19, cf = i - row * 19;
    const int bit = (row >> 2) & 1;
    const int gf = cf - 1 - bit;  // global float4 index
    const int h = row - 3;
    float4 v = {0.f, 0.f, 0.f, 0.f};
    if ((unsigned)h < 64u && (unsigned)gf < 16u) v = *(const float4*)(plane + h * 64 + gf * 4);
    *(float4*)(patch + row * 76 + cf * 4) = v;
  }
  const float* wp = cw + c * 49;  // block-uniform -> SGPR loads
  float wt[49];
#pragma unroll
  for (int i = 0; i < 49; ++i) wt[i] = wp[i];
  const float bias = cb[c];
  __syncthreads();
  const int j = t & 7, i = t >> 3;  // w0 = 8j, output rows 2i, 2i+1
  const int w0 = j * 8, h0 = i * 2;
  float acc[2][8];
#pragma unroll
  for (int dr = 0; dr < 2; ++dr)
#pragma unroll
    for (int ww = 0; ww < 8; ++ww) acc[dr][ww] = bias;
#pragma unroll
  for (int r = 0; r < 8; ++r) {  // patch rows h0 .. h0+7 (global h0-3 .. h0+4)
    const int prow = h0 + r;
    const int bit = (prow >> 2) & 1;
    const float* base = patch + prow * 76 + w0 + 4 * bit;
    float win[16];
#pragma unroll
    for (int q = 0; q < 4; ++q) {
      const float4 v = *(const float4*)(base + q * 4);
      win[q * 4 + 0] = v.x; win[q * 4 + 1] = v.y;
      win[q * 4 + 2] = v.z; win[q * 4 + 3] = v.w;
    }
#pragma unroll
    for (int dr = 0; dr < 2; ++dr) {
      const int kh = r - dr;
      if (kh >= 0 && kh < 7) {
#pragma unroll
        for (int kw = 0; kw < 7; ++kw) {
          const float wv = wt[kh * 7 + kw];
#pragma unroll
          for (int ww = 0; ww < 8; ++ww)
            acc[dr][ww] = fmaf(win[ww + kw + 1], wv, acc[dr][ww]);
        }
      }
    }
  }
  float* op = out + (size_t)bx * 4096;
#pragma unroll
  for (int dr = 0; dr < 2; ++dr) {
    const int hh = h0 + dr;
    float4 o1, o2;
    o1.x = acc[dr][0]; o1.y = acc[dr][1]; o1.z = acc[dr][2]; o1.w = acc[dr][3];
    o2.x = acc[dr][4]; o2.y = acc[dr][5]; o2.z = acc[dr][6]; o2.w = acc[dr][7];
    *(float4*)(op + hh * 64 + w0) = o1;
    *(float4*)(op + hh * 64 + w0 + 4) = o2;
  }
}

// ---------- LN over channels from NCHW, via LDS transpose -> NHWC bf16 hi/lo ----------
// 32 px per block; T[c][p] pitch 33
__global__ __launch_bounds__(256) void k_lnT(const float* __restrict__ src,
                                             const float* __restrict__ g,
                                             const float* __restrict__ bt,
                                             u16* __restrict__ Rh, u16* __restrict__ Rl,
                                             const int wlo) {
  __shared__ float T[256 * 33];
  __shared__ float red[8 * 32];
  __shared__ float gs[256], bs[256];
  const int t = threadIdx.x;
  const int n0 = blockIdx.x * 32;
  const int b = n0 >> 12, pl = n0 & 4095;
  gs[t] = g[t];
  bs[t] = bt[t];
  const int m = t & 7, h = t >> 3;  // m: px quad, h: channel-in-group
  const float* sp = src + (((size_t)(b * 256)) << 12) + pl + m * 4;
#pragma unroll
  for (int it = 0; it < 8; ++it) {
    const int c = it * 32 + h;
    const float4 v = *(const float4*)(sp + ((size_t)c << 12));
    *(float4*)(T + c * 33 + m * 4) = v;
  }
  __syncthreads();
  const int p = t & 31, qq = t >> 5;
  float s = 0.f;
#pragma unroll
  for (int jj = 0; jj < 32; ++jj) s += T[(qq * 32 + jj) * 33 + p];
  red[qq * 32 + p] = s;
  __syncthreads();
  float tot = 0.f;
#pragma unroll
  for (int k = 0; k < 8; ++k) tot += red[k * 32 + p];
  const float mu = tot * (1.0f / 256.0f);
  __syncthreads();
  float s2 = 0.f;
#pragma unroll
  for (int jj = 0; jj < 32; ++jj) {
    const float d = T[(qq * 32 + jj) * 33 + p] - mu;
    s2 = fmaf(d, d, s2);
  }
  red[qq * 32 + p] = s2;
  __syncthreads();
  float tot2 = 0.f;
#pragma unroll
  for (int k = 0; k < 8; ++k) tot2 += red[k * 32 + p];
  const float rs = 1.0f / sqrtf(tot2 * (1.0f / 256.0f) + 1e-5f);
#pragma unroll
  for (int jj = 0; jj < 32; ++jj) {
    const int c = qq * 32 + jj;
    const float y = (T[c * 33 + p] - mu) * rs * gs[c] + bs[c];
    const u16 hh = bfhi(y);
    const u16 ll = bfhi(y - b2f(hh));
    ((unsigned*)T)[c * 33 + p] = ((unsigned)hh << 16) | ll;
  }
  __syncthreads();
  const int w = t >> 6, l = t & 63;
  const unsigned* Tu = (const unsigned*)T;
#pragma unroll
  for (int r = 0; r < 4; ++r) {
    const int px = r * 8 + w * 2 + (l >> 5);
    const int c0 = (l & 31) * 8;
    unsigned hp[4], lp[4];
#pragma unroll
    for (int jj = 0; jj < 4; ++jj) {
      const unsigned a = Tu[(c0 + 2 * jj) * 33 + px];
      const unsigned bb = Tu[(c0 + 2 * jj + 1) * 33 + px];
      hp[jj] = (a >> 16) | (bb & 0xffff0000u);
      lp[jj] = (a & 0xffffu) | (bb << 16);
    }
    const size_t base = (size_t)(n0 + px) * 256 + c0;
    *(uint4*)(Rh + base) = make_uint4(hp[0], hp[1], hp[2], hp[3]);
    if (wlo) *(uint4*)(Rl + base) = make_uint4(lp[0], lp[1], lp[2], lp[3]);
  }
}

// ---------- fused-term MFMA GEMM: C = (Ah+Al) * (Bh+Bl)^T (drop lo*lo) ----------
// SPLIT: SINGLE-buffered 32KB staging (BK=32) -> 5 blocks/CU (4 for EPI=1).
//   Loop: [sync] stage -> sync -> ds_read+MFMA. The stage stall is hidden by
//   cross-block TLP (m97 regime: >=3 blocks/CU), not intra-block pipelining.
// non-SPLIT: 2-phase double-buffered 32KB pipeline (verified R2 schedule).
// LDS swizzle: slot = ((row>>1)&3)^quad over 64B rows (period 8, conflict-free, HW-verified).
// Block id remap: XCD = rowt%8, colt fastest in dispatch order -> A-tile L2-resident.
// EPI 0: fc1 (+bias, GELU, split->Mh/Ml, GRN sumsq atomics)
// EPI 1: fc2 (+bias, +xin NCHW residual via LDS transpose; xout NCHW and/or Eh/El rows)
// EPI 2: vq  (d2 = (tn - 2a) + c2, packed u64 atomicMin per row)
template <int KD, int SPLIT, int EPI, int NCT>
__global__ __launch_bounds__(256) void k_gemm(
    const u16* __restrict__ Ah_, const u16* __restrict__ Al_,
    const u16* __restrict__ Bh_, const u16* __restrict__ Bl_,
    const int row0, const long long bstride,
    const float* __restrict__ pbias,
    u16* __restrict__ poh, u16* __restrict__ pol,
    float* __restrict__ pxout, const float* __restrict__ pxin,
    float* __restrict__ pgx2, u64* __restrict__ pmin) {
  constexpr int BUF_B = (SPLIT ? 4 : 2) * 8192;  // bytes per staging buffer
  constexpr int NBUF = SPLIT ? 1 : 2;            // split: single-buffer for occupancy
  constexpr int STAGE_B = NBUF * BUF_B;
  constexpr int TRANS_B = (EPI == 1) ? 64 * 129 * 4 : 0;
  constexpr int SMEM_B = STAGE_B > TRANS_B ? STAGE_B : TRANS_B;
  constexpr int NS = KD / 32;
  __shared__ __align__(16) char smem[SMEM_B];

  const int t = threadIdx.x;
  const int w = t >> 6, l = t & 63;
  const int quad = l >> 4, lm = l & 15;
  const int wr = (w & 1) * 64, wc = (w >> 1) * 64;
  // linear block id -> (rowt, colt): colt fastest among dispatch, XCD(id%8)=rowt%8
  const int id = blockIdx.x + gridDim.x * blockIdx.y;
  constexpr int L = (NCT == 8) ? 3 : 1;
  const int colt = (id >> 3) & (NCT - 1);
  const int rowt = (id & 7) + ((id >> (3 + L)) << 3);
  const int nblk0 = rowt * 128;
  const int bglob = (row0 + nblk0) >> 12;

  const u16* Agh = Ah_ + (size_t)nblk0 * KD;
  const u16* Agl = SPLIT ? (Al_ + (size_t)nblk0 * KD) : Ah_;
  const u16* Bgh = Bh_ + (size_t)bglob * (size_t)bstride + (size_t)(colt * 128) * KD;
  const u16* Bgl = SPLIT ? (Bl_ + (size_t)bglob * (size_t)bstride + (size_t)(colt * 128) * KD) : Bh_;

  f32x4 acc[4][4];
  const f32x4 zz = {0.f, 0.f, 0.f, 0.f};
#pragma unroll
  for (int i = 0; i < 4; ++i)
#pragma unroll
    for (int j = 0; j < 4; ++j) acc[i][j] = zz;

  // stage one 8KB slab (128 rows x 32 K bf16); LDS dest linear, source pre-swizzled
  auto stage32 = [&](char* Sp, const u16* Gp, int ks) {
#pragma unroll
    for (int ii = 0; ii < 2; ++ii) {
      const int o = ii * 4096 + t * 16;                // byte offset in slab
      const int row = o >> 6;                          // 64B per row
      const int lc = ((o >> 4) & 3) ^ ((row >> 1) & 3);  // logical 16B chunk
      gload16(Sp + o, Gp + (size_t)row * KD + ks * 32 + lc * 8);
    }
  };
  auto stage_all = [&](int b, int ks) {
    char* base = smem + (size_t)b * BUF_B;
    stage32(base, Agh, ks);
    stage32(base + 8192, Bgh, ks);
    if constexpr (SPLIT) {
      stage32(base + 16384, Agl, ks);
      stage32(base + 24576, Bgl, ks);
    }
  };
  // swizzled fragment read: row rc, logical K-chunk = quad
  auto frag_at = [&](const u16* S, int rc) -> bf16x8 {
    const int sw = ((rc >> 1) & 3) ^ quad;
    return *(const bf16x8*)(S + rc * 32 + (sw << 3));
  };

  if constexpr (SPLIT) {
    // single-buffer: stage -> drain -> compute; TLP across 4-5 blocks/CU hides the drain
#pragma unroll 1
    for (int ks = 0; ks < NS; ++ks) {
      if (ks) __syncthreads();  // all waves' ds_reads of prev tile complete
      stage_all(0, ks);
      __syncthreads();          // stage landed (vmcnt0+lgkmcnt0 drain)
      const u16* base = (const u16*)smem;
      bf16x8 ah[4], bh[4], al[4], bl[4];
#pragma unroll
      for (int i = 0; i < 4; ++i) {
        ah[i] = frag_at(base, wr + i * 16 + lm);
        bh[i] = frag_at(base + 4096, wc + i * 16 + lm);
      }
#pragma unroll
      for (int i = 0; i < 4; ++i) {
        al[i] = frag_at(base + 8192, wr + i * 16 + lm);
        bl[i] = frag_at(base + 12288, wc + i * 16 + lm);
      }
#pragma unroll
      for (int i = 0; i < 4; ++i)
#pragma unroll
        for (int j = 0; j < 4; ++j)
          acc[i][j] = __builtin_amdgcn_mfma_f32_16x16x32_bf16(ah[i], bh[j], acc[i][j], 0, 0, 0);
#pragma unroll
      for (int i = 0; i < 4; ++i)
#pragma unroll
        for (int j = 0; j < 4; ++j)
          acc[i][j] = __builtin_amdgcn_mfma_f32_16x16x32_bf16(al[i], bh[j], acc[i][j], 0, 0, 0);
#pragma unroll
      for (int i = 0; i < 4; ++i)
#pragma unroll
        for (int j = 0; j < 4; ++j)
          acc[i][j] = __builtin_amdgcn_mfma_f32_16x16x32_bf16(ah[i], bl[j], acc[i][j], 0, 0, 0);
    }
  } else {
    // double-buffered 2-phase pipeline (verified schedule)
    stage_all(0, 0);
    __syncthreads();
#pragma unroll 1
    for (int ks = 0; ks < NS; ++ks) {
      const u16* base = (const u16*)(smem + (size_t)(ks & 1) * BUF_B);
      bf16x8 ah[4], bh[4];
#pragma unroll
      for (int i = 0; i < 4; ++i) {
        ah[i] = frag_at(base, wr + i * 16 + lm);
        bh[i] = frag_at(base + 4096, wc + i * 16 + lm);
      }
      // issue next-tile prefetch while this tile's MFMAs run
      if (ks + 1 < NS) stage_all((ks + 1) & 1, ks + 1);
      __builtin_amdgcn_sched_barrier(0);  // keep gloads above the MFMA cluster
#pragma unroll
      for (int i = 0; i < 4; ++i)
#pragma unroll
        for (int j = 0; j < 4; ++j)
          acc[i][j] = __builtin_amdgcn_mfma_f32_16x16x32_bf16(ah[i], bh[j], acc[i][j], 0, 0, 0);
      __syncthreads();  // vmcnt(0)+lgkmcnt(0) drain: prefetch lands, buffer handoff
    }
  }

  if constexpr (EPI == 0) {
    float csum[4] = {0.f, 0.f, 0.f, 0.f};
    float bv[4];
#pragma unroll
    for (int j = 0; j < 4; ++j) bv[j] = pbias[colt * 128 + wc + j * 16 + lm];
#pragma unroll
    for (int i = 0; i < 4; ++i) {
#pragma unroll
      for (int r = 0; r < 4; ++r) {
        const int row = nblk0 + wr + i * 16 + quad * 4 + r;
#pragma unroll
        for (int j = 0; j < 4; ++j) {
          const int col = colt * 128 + wc + j * 16 + lm;
          const float x = acc[i][j][r] + bv[j];
          const float gl = 0.5f * x * (1.0f + erff(x * 0.70710678118654752f));
          csum[j] = fmaf(gl, gl, csum[j]);
          const size_t idx = (size_t)row * 1024 + col;
          const u16 h = bfhi(gl);
          poh[idx] = h;
          if constexpr (SPLIT) pol[idx] = bfhi(gl - b2f(h));
        }
      }
    }
#pragma unroll
    for (int j = 0; j < 4; ++j) {
      float cs = csum[j];
      cs += __shfl_xor(cs, 16);
      cs += __shfl_xor(cs, 32);
      if (quad == 0)
        unsafeAtomicAdd(&pgx2[bglob * 1024 + colt * 128 + wc + j * 16 + lm], cs);
    }
  } else if constexpr (EPI == 1) {
    float* T = (float*)smem;  // [64 cols][pitch 129] f32, per col-half
    const int pg0 = (row0 + nblk0) & 4095;
    const int bb = (row0 + nblk0) >> 12;
#pragma unroll 1
    for (int h = 0; h < 2; ++h) {
      __syncthreads();
      if ((w >> 1) == h) {
#pragma unroll
        for (int i = 0; i < 4; ++i) {
          const int row = wr + i * 16 + quad * 4;
#pragma unroll
          for (int j = 0; j < 4; ++j) {
            const int cl = j * 16 + lm;
#pragma unroll
            for (int r = 0; r < 4; ++r) T[cl * 129 + row + r] = acc[i][j][r];
          }
        }
      }
      __syncthreads();
      const int lp = (l & 31) * 4;
      const int ch2 = l >> 5;
#pragma unroll
      for (int step = 0; step < 8; ++step) {
        const int cl = w * 16 + step * 2 + ch2;
        const int cg = colt * 128 + h * 64 + cl;
        float4 tv = *(float4*)&T[cl * 129 + lp];
        const float bv2 = pbias[cg];
        const size_t nchw = (((size_t)(bb * 256 + cg)) << 12) + pg0 + lp;
        const float4 xv = *(const float4*)(pxin + nchw);
        float4 z;
        z.x = tv.x + bv2 + xv.x;
        z.y = tv.y + bv2 + xv.y;
        z.z = tv.z + bv2 + xv.z;
        z.w = tv.w + bv2 + xv.w;
        if (pxout) *(float4*)(pxout + nchw) = z;
        if (poh) *(float4*)&T[cl * 129 + lp] = z;
      }
      if (poh) {
        __syncthreads();
        const int cl3 = t & 63;
        const int cg3 = colt * 128 + h * 64 + cl3;
        const int r0 = (t >> 6) * 32;
#pragma unroll
        for (int n = 0; n < 32; ++n) {
          const float z = T[cl3 * 129 + r0 + n];
          const size_t idx = (size_t)(nblk0 + r0 + n) * 256 + cg3;
          const u16 hh = bfhi(z);
          poh[idx] = hh;
          pol[idx] = bfhi(z - b2f(hh));
        }
      }
    }
  } else {
#pragma unroll
    for (int i = 0; i < 4; ++i) {
#pragma unroll
      for (int r = 0; r < 4; ++r) {
        const int nloc = nblk0 + wr + i * 16 + quad * 4 + r;
        const float tnv = pxin[nloc];
        u64 best = ~0ULL;
#pragma unroll
        for (int j = 0; j < 4; ++j) {
          const int code = colt * 128 + wc + j * 16 + lm;
          const float d = __fadd_rn(__fsub_rn(tnv, __fmul_rn(2.0f, acc[i][j][r])), pbias[code]);
          const u64 pk = (((u64)__float_as_uint(d)) << 32) | (unsigned)code;
          best = pk < best ? pk : best;
        }
#pragma unroll
        for (int off = 1; off < 16; off <<= 1) {
          unsigned lo32 = (unsigned)best, hi32 = (unsigned)(best >> 32);
          lo32 = __shfl_xor(lo32, off);
          hi32 = __shfl_xor(hi32, off);
          const u64 o2 = (((u64)hi32) << 32) | lo32;
          best = o2 < best ? o2 : best;
        }
        if (lm == 0) atomicMin(pmin + nloc, best);
      }
    }
  }
}

// ---------- row sumsq (tn) from bf16 hi/lo E rows ----------
__global__ __launch_bounds__(256) void k_rownorm(const u16* __restrict__ Eh,
                                                 const u16* __restrict__ El,
                                                 float* __restrict__ tn) {
  const int t = threadIdx.x;
  const int r = t >> 2, p = t & 3;
  const int n = blockIdx.x * 64 + r;
  const u16* ph = Eh + (size_t)n * 256 + p * 64;
  const u16* pl = El + (size_t)n * 256 + p * 64;
  float s = 0.f;
#pragma unroll
  for (int j = 0; j < 8; ++j) {
    const uint4 hv = *(const uint4*)(ph + j * 8);
    const uint4 lv = *(const uint4*)(pl + j * 8);
    const unsigned hu[4] = {hv.x, hv.y, hv.z, hv.w};
    const unsigned lu[4] = {lv.x, lv.y, lv.z, lv.w};
#pragma unroll
    for (int q = 0; q < 4; ++q) {
      const float v0 = b2f((u16)(hu[q] & 0xffff)) + b2f((u16)(lu[q] & 0xffff));
      const float v1 = b2f((u16)(hu[q] >> 16)) + b2f((u16)(lu[q] >> 16));
      s = fmaf(v0, v0, s);
      s = fmaf(v1, v1, s);
    }
  }
  s += __shfl_xor(s, 1);
  s += __shfl_xor(s, 2);
  if (p == 0) tn[n] = s;
}

// ---------- GRN scale s = 1 + gg*nx from sumsq ----------
__global__ __launch_bounds__(256) void k_grn_scale(const float* __restrict__ GX2,
                                                   const float* __restrict__ gg,
                                                   float* __restrict__ S, int b0) {
  const int b = b0 + blockIdx.x, t = threadIdx.x;
  const float* gxb = GX2 + (size_t)b * 1024;
  float gx[4];
  float s = 0.f;
#pragma unroll
  for (int i = 0; i < 4; ++i) {
    gx[i] = sqrtf(gxb[t + i * 256]);
    s += gx[i];
  }
  const int w = t >> 6, l = t & 63;
#pragma unroll
  for (int o = 32; o > 0; o >>= 1) s += __shfl_down(s, o);
  __shared__ float red[4];
  __shared__ float bc;
  if (l == 0) red[w] = s;
  __syncthreads();
  if (t == 0) bc = 1.0f / ((red[0] + red[1] + red[2] + red[3]) * (1.0f / 1024.0f) + 1e-6f);
  __syncthreads();
  const float inv = bc;
#pragma unroll
  for (int i = 0; i < 4; ++i)
    S[(size_t)b * 1024 + t + i * 256] = fmaf(gg[t + i * 256], gx[i] * inv, 1.0f);
}

// ---------- per-batch scaled+split+transposed W2 ----------
__global__ __launch_bounds__(256) void k_w2prep(const float* __restrict__ W2,
                                                const float* __restrict__ S, int b0,
                                                u16* __restrict__ Wh, u16* __restrict__ Wl) {
  const int bx = blockIdx.x;
  const int b = b0 + (bx >> 8), n = bx & 255;
  const int t = threadIdx.x;
#pragma unroll
  for (int j = 0; j < 4; ++j) {
    const int k = t + j * 256;
    const float v = W2[(size_t)k * 256 + n] * S[(size_t)b * 1024 + k];
    const size_t idx = ((size_t)(b * 256 + n)) * 1024 + k;
    const u16 h = bfhi(v);
    Wh[idx] = h;
    Wl[idx] = bfhi(v - b2f(h));
  }
}

// ---------- bias2v = b2 + gb @ W2 (one block per output channel) ----------
__global__ __launch_bounds__(256) void k_bias2(const float* __restrict__ W2,
                                               const float* __restrict__ gb,
                                               const float* __restrict__ b2,
                                               float* __restrict__ out) {
  const int c = blockIdx.x, t = threadIdx.x;
  float acc = 0.f;
#pragma unroll
  for (int j = 0; j < 4; ++j) {
    const int k = t + j * 256;
    acc = fmaf(gb[k], W2[(size_t)k * 256 + c], acc);
  }
  const int w = t >> 6, l = t & 63;
#pragma unroll
  for (int o = 32; o > 0; o >>= 1) acc += __shfl_down(acc, o);
  __shared__ float red[4];
  if (l == 0) red[w] = acc;
  __syncthreads();
  if (t == 0) out[c] = red[0] + red[1] + red[2] + red[3] + b2[c];
}

// ---------- W1^T split ----------
__global__ __launch_bounds__(256) void k_wt(const float* __restrict__ W1,
                                            u16* __restrict__ Wh, u16* __restrict__ Wl) {
  const int bx = blockIdx.x;  // d*1024 + n
  const int d = bx >> 10, n = bx & 1023;
  const int k = threadIdx.x;
  const float v = W1[(size_t)d * 262144 + (size_t)k * 1024 + n];
  const size_t idx = (size_t)bx * 256 + k;
  const u16 h = bfhi(v);
  Wh[idx] = h;
  Wl[idx] = bfhi(v - b2f(h));
}

// ---------- codebook split ----------
__global__ __launch_bounds__(256) void k_csplit(const float* __restrict__ C,
                                                u16* __restrict__ Ch, u16* __restrict__ Cl) {
  const size_t i = (size_t)blockIdx.x * 256 + threadIdx.x;
  const float v = C[i];
  const u16 h = bfhi(v);
  Ch[i] = h;
  Cl[i] = bfhi(v - b2f(h));
}

// ---------- numpy-pairwise |c|^2 per code ----------
__device__ __forceinline__ float np_pairwise_sq_256(const float* p) {
  float half[2];
#pragma unroll
  for (int hh = 0; hh < 2; ++hh) {
    float r[8];
#pragma unroll
    for (int j = 0; j < 8; ++j) {
      const float v = p[hh * 128 + j];
      r[j] = __fmul_rn(v, v);
    }
    for (int i = 8; i < 128; i += 8) {
#pragma unroll
      for (int j = 0; j < 8; ++j) {
        const float v = p[hh * 128 + i + j];
        r[j] = __fadd_rn(r[j], __fmul_rn(v, v));
      }
    }
    half[hh] = __fadd_rn(__fadd_rn(__fadd_rn(r[0], r[1]), __fadd_rn(r[2], r[3])),
                         __fadd_rn(__fadd_rn(r[4], r[5]), __fadd_rn(r[6], r[7])));
  }
  return __fadd_rn(half[0], half[1]);
}

__global__ __launch_bounds__(256) void k_c2(const float* __restrict__ cbk, float* __restrict__ c2) {
  const int k = blockIdx.x * 256 + threadIdx.x;
  c2[k] = np_pairwise_sq_256(cbk + (size_t)k * 256);
}

// ---------- index output + quantized gather ----------
__global__ __launch_bounds__(256) void k_idx(const u64* __restrict__ pk, float* __restrict__ outI) {
  const int n = blockIdx.x * 256 + threadIdx.x;
  outI[n] = (float)(unsigned)(pk[n] & 0xffffffffULL);
}

// 64 consecutive pixels per block; lanes = pixels so NCHW writes coalesce
__global__ __launch_bounds__(256) void k_gather(const u64* __restrict__ pk,
                                                const float* __restrict__ cbk,
                                                float* __restrict__ outq) {
  const int t = threadIdx.x;
  const int p0 = blockIdx.x * 64;
  const int b = p0 >> 12, pl = (p0 & 4095) + (t & 63);
  const int cg = t >> 6;  // 4 channel groups of 64
  const int n = p0 + (t & 63);
  const int k = (int)(unsigned)(pk[n] & 0xffffffffULL);
  const float* crow = cbk + (size_t)k * 256 + cg * 64;
  float* ob = outq + (((size_t)(b * 256 + cg * 64)) << 12) + pl;
#pragma unroll 1
  for (int j = 0; j < 16; ++j) {
    const float4 cv = *(const float4*)(crow + j * 4);
    ob[((size_t)(j * 4 + 0)) << 12] = cv.x;
    ob[((size_t)(j * 4 + 1)) << 12] = cv.y;
    ob[((size_t)(j * 4 + 2)) << 12] = cv.z;
    ob[((size_t)(j * 4 + 3)) << 12] = cv.w;
  }
}

extern "C" void kernel_launch(void* const* d_in, const int* in_sizes, int n_in,
                              void* d_out, int out_size, void* d_ws, size_t ws_size,
                              hipStream_t stream) {
  const float* x = (const float*)d_in[0];
  const float* cbk = (const float*)d_in[1];
  const float* Pe[10];
  const float* Pd[10];
  for (int i = 0; i < 10; ++i) Pe[i] = (const float*)d_in[2 + i];
  for (int i = 0; i < 10; ++i) Pd[i] = (const float*)d_in[12 + i];
  // order per dict: conv_w, conv_b, ln_g, ln_b, fc1_w, fc1_b, grn_g, grn_b, fc2_w, fc2_b

  float* ws = (float*)d_ws;
  size_t o = 0;
  auto alloc = [&](size_t nf) {
    float* p = ws + o;
    o += (nf + 63) & ~(size_t)63;
    return p;
  };
  float* P1 = alloc(8388608);      // NCHW ping
  u16* Rh = (u16*)alloc(4194304);  // rows hi (also E hi)
  u16* Rl = (u16*)alloc(4194304);  // rows lo (also E lo)
  u16* W1th_e = (u16*)alloc(262144);
  u16* W1tl_e = (u16*)alloc(262144);
  u16* W1th_d = (u16*)alloc(262144);
  u16* W1tl_d = (u16*)alloc(262144);
  u16* W2sh = (u16*)alloc(1048576);
  u16* W2sl = (u16*)alloc(1048576);
  u16* Ch = (u16*)alloc(131072);
  u16* Cl = (u16*)alloc(131072);
  float* C2v = alloc(1024);
  float* GX2 = alloc(8192);
  float* Sv = alloc(8192);
  float* bias2v = alloc(256);
  float* tn = alloc(32768);
  u64* pk = (u64*)alloc(65536);
  const size_t fixedf = o;
  const size_t availf = (ws_size / 4 > fixedf) ? ws_size / 4 - fixedf : 0;
  int chunkB = (int)(availf / 4194304);  // Mh+Ml per batch = 4M floats worth
  if (chunkB > 8) chunkB = 8;
  if (chunkB < 1) chunkB = 1;
  float* Cv = ws + o;  // conv NCHW fp32, aliases M arena (dead by fc1 time)
  u16* Mh = (u16*)(ws + o);
  u16* Ml = (u16*)(ws + o + (size_t)chunkB * 2097152);

  float* outQ = (float*)d_out;
  float* outD = outQ + 8388608;
  float* outI = outD + 8388608;

  auto run_enc = [&](const float* xin, float* xout, u16* Eh, u16* El,
                     const float* const* pp, int d) {
    k_conv<<<2048, 256, 0, stream>>>(xin, pp[0] + (size_t)d * 256 * 49, pp[1] + d * 256, Cv);
    k_lnT<<<1024, 256, 0, stream>>>(Cv, pp[2] + d * 256, pp[3] + d * 256, Rh, Rl, 1);
    k_bias2<<<256, 256, 0, stream>>>(pp[8] + (size_t)d * 262144, pp[7] + d * 1024,
                                     pp[9] + d * 256, bias2v);
    hipMemsetAsync(GX2, 0, 8192 * 4, stream);
    for (int b0 = 0; b0 < 8; b0 += chunkB) {
      const int nb = (8 - b0 < chunkB) ? 8 - b0 : chunkB;
      k_gemm<256, 1, 0, 8><<<dim3(8, nb * 32), 256, 0, stream>>>(
          Rh + (size_t)b0 * 4096 * 256, Rl + (size_t)b0 * 4096 * 256,
          W1th_e + (size_t)d * 262144, W1tl_e + (size_t)d * 262144,
          b0 * 4096, 0, Pe[5] + d * 1024, Mh, Ml, nullptr, nullptr, GX2, nullptr);
      k_grn_scale<<<nb, 256, 0, stream>>>(GX2, pp[6] + d * 1024, Sv, b0);
      k_w2prep<<<nb * 256, 256, 0, stream>>>(pp[8] + (size_t)d * 262144, Sv, b0, W2sh, W2sl);
      k_gemm<1024, 1, 1, 2><<<dim3(2, nb * 32), 256, 0, stream>>>(
          Mh, Ml, W2sh, W2sl, b0 * 4096, 262144LL, bias2v,
          Eh ? Eh + (size_t)b0 * 4096 * 256 : (u16*)nullptr,
          El ? El + (size_t)b0 * 4096 * 256 : (u16*)nullptr,
          xout, xin, nullptr, nullptr);
    }
  };

  auto run_dec = [&](const float* xin, float* xout, const float* const* pp, int d) {
    k_conv<<<2048, 256, 0, stream>>>(xin, pp[0] + (size_t)d * 256 * 49, pp[1] + d * 256, Cv);
    k_lnT<<<1024, 256, 0, stream>>>(Cv, pp[2] + d * 256, pp[3] + d * 256, Rh, Rl, 0);
    k_bias2<<<256, 256, 0, stream>>>(pp[8] + (size_t)d * 262144, pp[7] + d * 1024,
                                     pp[9] + d * 256, bias2v);
    hipMemsetAsync(GX2, 0, 8192 * 4, stream);
    for (int b0 = 0; b0 < 8; b0 += chunkB) {
      const int nb = (8 - b0 < chunkB) ? 8 - b0 : chunkB;
      k_gemm<256, 0, 0, 8><<<dim3(8, nb * 32), 256, 0, stream>>>(
          Rh + (size_t)b0 * 4096 * 256, nullptr,
          W1th_d + (size_t)d * 262144, nullptr,
          b0 * 4096, 0, Pd[5] + d * 1024, Mh, nullptr, nullptr, nullptr, GX2, nullptr);
      k_grn_scale<<<nb, 256, 0, stream>>>(GX2, pp[6] + d * 1024, Sv, b0);
      k_w2prep<<<nb * 256, 256, 0, stream>>>(pp[8] + (size_t)d * 262144, Sv, b0, W2sh, W2sl);
      k_gemm<1024, 0, 1, 2><<<dim3(2, nb * 32), 256, 0, stream>>>(
          Mh, nullptr, W2sh, nullptr, b0 * 4096, 262144LL, bias2v,
          nullptr, nullptr, xout, xin, nullptr, nullptr);
    }
  };

  // prep
  k_wt<<<2048, 256, 0, stream>>>(Pe[4], W1th_e, W1tl_e);
  k_wt<<<2048, 256, 0, stream>>>(Pd[4], W1th_d, W1tl_d);
  k_csplit<<<1024, 256, 0, stream>>>(cbk, Ch, Cl);
  k_c2<<<4, 256, 0, stream>>>(cbk, C2v);

  // encoder (split-bf16, fused 3-term)
  run_enc(x, P1, nullptr, nullptr, Pe, 0);
  run_enc(P1, nullptr, Rh, Rl, Pe, 1);  // E -> Rh/Rl, no NCHW out

  // VQ
  k_rownorm<<<512, 256, 0, stream>>>(Rh, Rl, tn);
  hipMemsetAsync(pk, 0xFF, 32768 * 8, stream);
  k_gemm<256, 1, 2, 8><<<dim3(8, 256), 256, 0, stream>>>(Rh, Rl, Ch, Cl, 0, 0,
                                                         C2v, nullptr, nullptr, nullptr,
                                                         tn, nullptr, pk);
  k_idx<<<128, 256, 0, stream>>>(pk, outI);
  k_gather<<<512, 256, 0, stream>>>(pk, cbk, outQ);

  // decoder (plain bf16)
  run_dec(outQ, P1, Pd, 0);
  run_dec(P1, outD, Pd, 1);
}

// Round 7
// 865.915 us; speedup vs baseline: 1.0945x; 1.0281x over previous
//
#include <hip/hip_runtime.h>
#include <math.h>
#include <stdint.h>

typedef unsigned short u16;
typedef unsigned long long u64;
typedef __attribute__((ext_vector_type(8))) short bf16x8;
typedef __attribute__((ext_vector_type(4))) float f32x4;

__device__ __forceinline__ u16 bfhi(float v) {
  unsigned u = __float_as_uint(v);
  u += 0x7FFFu + ((u >> 16) & 1u);
  return (u16)(u >> 16);
}
__device__ __forceinline__ float b2f(u16 h) { return __uint_as_float((unsigned)h << 16); }

__device__ __forceinline__ void gload16(void* lds, const void* g) {
  __builtin_amdgcn_global_load_lds(
      (const __attribute__((address_space(1))) unsigned int*)g,
      (__attribute__((address_space(3))) unsigned int*)lds, 16, 0, 0);
}

// ---------- depthwise conv 7x7 + bias: NCHW -> NCHW (coalesced float4 stores) ----------
__global__ __launch_bounds__(256) void k_conv(const float* __restrict__ in,
                                              const float* __restrict__ cw,
                                              const float* __restrict__ cb,
                                              float* __restrict__ out) {
  const int bx = blockIdx.x;  // 8b x 256c
  const int c = bx & 255;
  __shared__ float patch[70 * 76];
  const int t = threadIdx.x;
  const float* plane = in + (size_t)bx * 4096;
  for (int i = t; i < 1330; i += 256) {
    const int row = i / 19, cf = i - row * 19;
    const int bit = (row >> 2) & 1;
    const int gf = cf - 1 - bit;
    const int h = row - 3;
    float4 v = {0.f, 0.f, 0.f, 0.f};
    if ((unsigned)h < 64u && (unsigned)gf < 16u) v = *(const float4*)(plane + h * 64 + gf * 4);
    *(float4*)(patch + row * 76 + cf * 4) = v;
  }
  const float* wp = cw + c * 49;
  float wt[49];
#pragma unroll
  for (int i = 0; i < 49; ++i) wt[i] = wp[i];
  const float bias = cb[c];
  __syncthreads();
  const int j = t & 7, i = t >> 3;
  const int w0 = j * 8, h0 = i * 2;
  float acc[2][8];
#pragma unroll
  for (int dr = 0; dr < 2; ++dr)
#pragma unroll
    for (int ww = 0; ww < 8; ++ww) acc[dr][ww] = bias;
#pragma unroll
  for (int r = 0; r < 8; ++r) {
    const int prow = h0 + r;
    const int bit = (prow >> 2) & 1;
    const float* base = patch + prow * 76 + w0 + 4 * bit;
    float win[16];
#pragma unroll
    for (int q = 0; q < 4; ++q) {
      const float4 v = *(const float4*)(base + q * 4);
      win[q * 4 + 0] = v.x; win[q * 4 + 1] = v.y;
      win[q * 4 + 2] = v.z; win[q * 4 + 3] = v.w;
    }
#pragma unroll
    for (int dr = 0; dr < 2; ++dr) {
      const int kh = r - dr;
      if (kh >= 0 && kh < 7) {
#pragma unroll
        for (int kw = 0; kw < 7; ++kw) {
          const float wv = wt[kh * 7 + kw];
#pragma unroll
          for (int ww = 0; ww < 8; ++ww)
            acc[dr][ww] = fmaf(win[ww + kw + 1], wv, acc[dr][ww]);
        }
      }
    }
  }
  float* op = out + (size_t)bx * 4096;
#pragma unroll
  for (int dr = 0; dr < 2; ++dr) {
    const int hh = h0 + dr;
    float4 o1, o2;
    o1.x = acc[dr][0]; o1.y = acc[dr][1]; o1.z = acc[dr][2]; o1.w = acc[dr][3];
    o2.x = acc[dr][4]; o2.y = acc[dr][5]; o2.z = acc[dr][6]; o2.w = acc[dr][7];
    *(float4*)(op + hh * 64 + w0) = o1;
    *(float4*)(op + hh * 64 + w0 + 4) = o2;
  }
}

// ---------- LN over channels from NCHW, via LDS transpose -> NHWC bf16 hi/lo ----------
__global__ __launch_bounds__(256) void k_lnT(const float* __restrict__ src,
                                             const float* __restrict__ g,
                                             const float* __restrict__ bt,
                                             u16* __restrict__ Rh, u16* __restrict__ Rl,
                                             const int wlo) {
  __shared__ float T[256 * 33];
  __shared__ float red[8 * 32];
  __shared__ float gs[256], bs[256];
  const int t = threadIdx.x;
  const int n0 = blockIdx.x * 32;
  const int b = n0 >> 12, pl = n0 & 4095;
  gs[t] = g[t];
  bs[t] = bt[t];
  const int m = t & 7, h = t >> 3;
  const float* sp = src + (((size_t)(b * 256)) << 12) + pl + m * 4;
#pragma unroll
  for (int it = 0; it < 8; ++it) {
    const int c = it * 32 + h;
    const float4 v = *(const float4*)(sp + ((size_t)c << 12));
    *(float4*)(T + c * 33 + m * 4) = v;
  }
  __syncthreads();
  const int p = t & 31, qq = t >> 5;
  float s = 0.f;
#pragma unroll
  for (int jj = 0; jj < 32; ++jj) s += T[(qq * 32 + jj) * 33 + p];
  red[qq * 32 + p] = s;
  __syncthreads();
  float tot = 0.f;
#pragma unroll
  for (int k = 0; k < 8; ++k) tot += red[k * 32 + p];
  const float mu = tot * (1.0f / 256.0f);
  __syncthreads();
  float s2 = 0.f;
#pragma unroll
  for (int jj = 0; jj < 32; ++jj) {
    const float d = T[(qq * 32 + jj) * 33 + p] - mu;
    s2 = fmaf(d, d, s2);
  }
  red[qq * 32 + p] = s2;
  __syncthreads();
  float tot2 = 0.f;
#pragma unroll
  for (int k = 0; k < 8; ++k) tot2 += red[k * 32 + p];
  const float rs = 1.0f / sqrtf(tot2 * (1.0f / 256.0f) + 1e-5f);
#pragma unroll
  for (int jj = 0; jj < 32; ++jj) {
    const int c = qq * 32 + jj;
    const float y = (T[c * 33 + p] - mu) * rs * gs[c] + bs[c];
    const u16 hh = bfhi(y);
    const u16 ll = bfhi(y - b2f(hh));
    ((unsigned*)T)[c * 33 + p] = ((unsigned)hh << 16) | ll;
  }
  __syncthreads();
  const int w = t >> 6, l = t & 63;
  const unsigned* Tu = (const unsigned*)T;
#pragma unroll
  for (int r = 0; r < 4; ++r) {
    const int px = r * 8 + w * 2 + (l >> 5);
    const int c0 = (l & 31) * 8;
    unsigned hp[4], lp[4];
#pragma unroll
    for (int jj = 0; jj < 4; ++jj) {
      const unsigned a = Tu[(c0 + 2 * jj) * 33 + px];
      const unsigned bb = Tu[(c0 + 2 * jj + 1) * 33 + px];
      hp[jj] = (a >> 16) | (bb & 0xffff0000u);
      lp[jj] = (a & 0xffffu) | (bb << 16);
    }
    const size_t base = (size_t)(n0 + px) * 256 + c0;
    *(uint4*)(Rh + base) = make_uint4(hp[0], hp[1], hp[2], hp[3]);
    if (wlo) *(uint4*)(Rl + base) = make_uint4(lp[0], lp[1], lp[2], lp[3]);
  }
}

// ---------- fused-term MFMA GEMM: C = (Ah+Al) * (Bh+Bl)^T (drop lo*lo) ----------
// A: staged global->LDS (swizzled, proven conflict-free). B: NOT staged --
//   producers pre-lay B in exact MFMA fragment order (1KB contiguous per wave
//   fragment: chunk = ((colt*2+wcw)*NS + ks)*4 + j, lane l holds
//   B[col=j*16+(l&15)][k=ks*32+(l>>4)*8 .. +8]); the loop reads bh/bl via
//   coalesced global_load_dwordx4 from L2. Halves staged bytes + ds_reads.
// M (EPI=0 output) is stored with per-64 K-permutation pi(j*16+lm)=lm*4+j so
//   each thread packs 4 cols into one 8B store; w2prepf applies pi^-1.
// Block id remap: XCD = rowt%8, colt fastest -> A-tile L2-resident.
template <int KD, int SPLIT, int EPI, int NCT>
__global__ __launch_bounds__(256) void k_gemm(
    const u16* __restrict__ Ah_, const u16* __restrict__ Al_,
    const u16* __restrict__ Bh_, const u16* __restrict__ Bl_,
    const int row0, const long long bstride,
    const float* __restrict__ pbias,
    u16* __restrict__ poh, u16* __restrict__ pol,
    float* __restrict__ pxout, const float* __restrict__ pxin,
    float* __restrict__ pgx2, u64* __restrict__ pmin) {
  constexpr int ABUF_B = (SPLIT ? 2 : 1) * 8192;  // A slabs only (hi [+lo])
  constexpr int NBUF = SPLIT ? 1 : 2;
  constexpr int STAGE_B = NBUF * ABUF_B;
  constexpr int TRANS_B = (EPI == 1) ? 64 * 129 * 4 : 0;
  constexpr int SMEM_B = STAGE_B > TRANS_B ? STAGE_B : TRANS_B;
  constexpr int NS = KD / 32;
  __shared__ __align__(16) char smem[SMEM_B];

  const int t = threadIdx.x;
  const int w = t >> 6, l = t & 63;
  const int quad = l >> 4, lm = l & 15;
  const int wr = (w & 1) * 64, wc = (w >> 1) * 64;
  const int id = blockIdx.x + gridDim.x * blockIdx.y;
  constexpr int L = (NCT == 8) ? 3 : 1;
  const int colt = (id >> 3) & (NCT - 1);
  const int rowt = (id & 7) + ((id >> (3 + L)) << 3);
  const int nblk0 = rowt * 128;
  const int bglob = (row0 + nblk0) >> 12;

  const u16* Agh = Ah_ + (size_t)nblk0 * KD;
  const u16* Agl = SPLIT ? (Al_ + (size_t)nblk0 * KD) : Ah_;
  // fragment-ordered B base for this wave's column half (wcw = w>>1)
  const size_t bfo = (size_t)bglob * (size_t)bstride +
                     (size_t)((colt * 2 + (w >> 1)) * NS * 4) * 512 + (size_t)l * 8;
  const u16* Bfh = Bh_ + bfo;
  const u16* Bfl = SPLIT ? (Bl_ + bfo) : Bfh;

  f32x4 acc[4][4];
  const f32x4 zz = {0.f, 0.f, 0.f, 0.f};
#pragma unroll
  for (int i = 0; i < 4; ++i)
#pragma unroll
    for (int j = 0; j < 4; ++j) acc[i][j] = zz;

  // stage one 8KB A slab (128 rows x 32 K bf16); LDS linear, source pre-swizzled
  auto stage32 = [&](char* Sp, const u16* Gp, int ks) {
#pragma unroll
    for (int ii = 0; ii < 2; ++ii) {
      const int o = ii * 4096 + t * 16;
      const int row = o >> 6;
      const int lc = ((o >> 4) & 3) ^ ((row >> 1) & 3);
      gload16(Sp + o, Gp + (size_t)row * KD + ks * 32 + lc * 8);
    }
  };
  auto frag_at = [&](const u16* S, int rc) -> bf16x8 {
    const int sw = ((rc >> 1) & 3) ^ quad;
    return *(const bf16x8*)(S + rc * 32 + (sw << 3));
  };

  if constexpr (SPLIT) {
    // single A buffer: [sync] stage A + issue B-frag loads -> sync -> ds_read + MFMA
#pragma unroll 1
    for (int ks = 0; ks < NS; ++ks) {
      if (ks) __syncthreads();  // prev tile's ds_reads done
      stage32(smem, Agh, ks);
      stage32(smem + 8192, Agl, ks);
      bf16x8 bh[4], bl[4];
#pragma unroll
      for (int i = 0; i < 4; ++i) bh[i] = *(const bf16x8*)(Bfh + (ks * 4 + i) * 512);
#pragma unroll
      for (int i = 0; i < 4; ++i) bl[i] = *(const bf16x8*)(Bfl + (ks * 4 + i) * 512);
      __syncthreads();  // stage + B loads landed (vmcnt0 drain)
      const u16* base = (const u16*)smem;
      bf16x8 ah[4], al[4];
#pragma unroll
      for (int i = 0; i < 4; ++i) {
        ah[i] = frag_at(base, wr + i * 16 + lm);
        al[i] = frag_at(base + 4096, wr + i * 16 + lm);
      }
#pragma unroll
      for (int i = 0; i < 4; ++i)
#pragma unroll
        for (int j = 0; j < 4; ++j)
          acc[i][j] = __builtin_amdgcn_mfma_f32_16x16x32_bf16(ah[i], bh[j], acc[i][j], 0, 0, 0);
#pragma unroll
      for (int i = 0; i < 4; ++i)
#pragma unroll
        for (int j = 0; j < 4; ++j)
          acc[i][j] = __builtin_amdgcn_mfma_f32_16x16x32_bf16(al[i], bh[j], acc[i][j], 0, 0, 0);
#pragma unroll
      for (int i = 0; i < 4; ++i)
#pragma unroll
        for (int j = 0; j < 4; ++j)
          acc[i][j] = __builtin_amdgcn_mfma_f32_16x16x32_bf16(ah[i], bl[j], acc[i][j], 0, 0, 0);
    }
  } else {
    // double-buffered A pipeline (verified 2-phase schedule), B direct per step
    stage32(smem, Agh, 0);
    __syncthreads();
#pragma unroll 1
    for (int ks = 0; ks < NS; ++ks) {
      const u16* base = (const u16*)(smem + (size_t)(ks & 1) * ABUF_B);
      bf16x8 ah[4], bh[4];
#pragma unroll
      for (int i = 0; i < 4; ++i) bh[i] = *(const bf16x8*)(Bfh + (ks * 4 + i) * 512);
#pragma unroll
      for (int i = 0; i < 4; ++i) ah[i] = frag_at(base, wr + i * 16 + lm);
      if (ks + 1 < NS) stage32(smem + (size_t)((ks + 1) & 1) * ABUF_B, Agh, ks + 1);
      __builtin_amdgcn_sched_barrier(0);  // keep loads above the MFMA cluster
#pragma unroll
      for (int i = 0; i < 4; ++i)
#pragma unroll
        for (int j = 0; j < 4; ++j)
          acc[i][j] = __builtin_amdgcn_mfma_f32_16x16x32_bf16(ah[i], bh[j], acc[i][j], 0, 0, 0);
      __syncthreads();  // prefetch lands, buffer handoff
    }
  }

  if constexpr (EPI == 0) {
    float csum[4] = {0.f, 0.f, 0.f, 0.f};
    float bv[4];
#pragma unroll
    for (int j = 0; j < 4; ++j) bv[j] = pbias[colt * 128 + wc + j * 16 + lm];
#pragma unroll
    for (int i = 0; i < 4; ++i) {
#pragma unroll
      for (int r = 0; r < 4; ++r) {
        const int row = nblk0 + wr + i * 16 + quad * 4 + r;
        unsigned hp[4], lp[4];
#pragma unroll
        for (int j = 0; j < 4; ++j) {
          const float x = acc[i][j][r] + bv[j];
          const float gl = 0.5f * x * (1.0f + erff(x * 0.70710678118654752f));
          csum[j] = fmaf(gl, gl, csum[j]);
          const u16 h = bfhi(gl);
          hp[j] = h;
          if constexpr (SPLIT) lp[j] = bfhi(gl - b2f(h));
        }
        // pi-packed: 4 cols -> one 8B store at col' = base + lm*4 + j
        const size_t ob = (size_t)row * 1024 + colt * 128 + wc + lm * 4;
        *(uint2*)(poh + ob) = make_uint2(hp[0] | (hp[1] << 16), hp[2] | (hp[3] << 16));
        if constexpr (SPLIT)
          *(uint2*)(pol + ob) = make_uint2(lp[0] | (lp[1] << 16), lp[2] | (lp[3] << 16));
      }
    }
#pragma unroll
    for (int j = 0; j < 4; ++j) {
      float cs = csum[j];
      cs += __shfl_xor(cs, 16);
      cs += __shfl_xor(cs, 32);
      if (quad == 0)
        unsafeAtomicAdd(&pgx2[bglob * 1024 + colt * 128 + wc + j * 16 + lm], cs);
    }
  } else if constexpr (EPI == 1) {
    float* T = (float*)smem;  // [64 cols][pitch 129] f32, per col-half
    const int pg0 = (row0 + nblk0) & 4095;
    const int bb = (row0 + nblk0) >> 12;
#pragma unroll 1
    for (int h = 0; h < 2; ++h) {
      __syncthreads();
      if ((w >> 1) == h) {
#pragma unroll
        for (int i = 0; i < 4; ++i) {
          const int row = wr + i * 16 + quad * 4;
#pragma unroll
          for (int j = 0; j < 4; ++j) {
            const int cl = j * 16 + lm;
#pragma unroll
            for (int r = 0; r < 4; ++r) T[cl * 129 + row + r] = acc[i][j][r];
          }
        }
      }
      __syncthreads();
      const int lp = (l & 31) * 4;
      const int ch2 = l >> 5;
#pragma unroll
      for (int step = 0; step < 8; ++step) {
        const int cl = w * 16 + step * 2 + ch2;
        const int cg = colt * 128 + h * 64 + cl;
        float4 tv = *(float4*)&T[cl * 129 + lp];
        const float bv2 = pbias[cg];
        const size_t nchw = (((size_t)(bb * 256 + cg)) << 12) + pg0 + lp;
        const float4 xv = *(const float4*)(pxin + nchw);
        float4 z;
        z.x = tv.x + bv2 + xv.x;
        z.y = tv.y + bv2 + xv.y;
        z.z = tv.z + bv2 + xv.z;
        z.w = tv.w + bv2 + xv.w;
        if (pxout) *(float4*)(pxout + nchw) = z;
        if (poh) *(float4*)&T[cl * 129 + lp] = z;
      }
      if (poh) {
        __syncthreads();
        // packed E store: 4 cols x u64, bank-safe row map (rows rg+16n)
        const int u = t & 15, c4 = u * 4;
        const int rg = t >> 4;  // 0..15
        const int cg4 = colt * 128 + h * 64 + c4;
#pragma unroll
        for (int n = 0; n < 8; ++n) {
          const int row = rg + 16 * n;
          unsigned hp[4], lp4[4];
#pragma unroll
          for (int q = 0; q < 4; ++q) {
            const float z = T[(c4 + q) * 129 + row];
            const u16 hh = bfhi(z);
            hp[q] = hh;
            lp4[q] = bfhi(z - b2f(hh));
          }
          const size_t idx = (size_t)(nblk0 + row) * 256 + cg4;
          *(uint2*)(poh + idx) = make_uint2(hp[0] | (hp[1] << 16), hp[2] | (hp[3] << 16));
          *(uint2*)(pol + idx) = make_uint2(lp4[0] | (lp4[1] << 16), lp4[2] | (lp4[3] << 16));
        }
      }
    }
  } else {
#pragma unroll
    for (int i = 0; i < 4; ++i) {
#pragma unroll
      for (int r = 0; r < 4; ++r) {
        const int nloc = nblk0 + wr + i * 16 + quad * 4 + r;
        const float tnv = pxin[nloc];
        u64 best = ~0ULL;
#pragma unroll
        for (int j = 0; j < 4; ++j) {
          const int code = colt * 128 + wc + j * 16 + lm;
          const float d = __fadd_rn(__fsub_rn(tnv, __fmul_rn(2.0f, acc[i][j][r])), pbias[code]);
          const u64 pk = (((u64)__float_as_uint(d)) << 32) | (unsigned)code;
          best = pk < best ? pk : best;
        }
#pragma unroll
        for (int off = 1; off < 16; off <<= 1) {
          unsigned lo32 = (unsigned)best, hi32 = (unsigned)(best >> 32);
          lo32 = __shfl_xor(lo32, off);
          hi32 = __shfl_xor(hi32, off);
          const u64 o2 = (((u64)hi32) << 32) | lo32;
          best = o2 < best ? o2 : best;
        }
        if (lm == 0) atomicMin(pmin + nloc, best);
      }
    }
  }
}

// ---------- row sumsq (tn) from bf16 hi/lo E rows ----------
__global__ __launch_bounds__(256) void k_rownorm(const u16* __restrict__ Eh,
                                                 const u16* __restrict__ El,
                                                 float* __restrict__ tn) {
  const int t = threadIdx.x;
  const int r = t >> 2, p = t & 3;
  const int n = blockIdx.x * 64 + r;
  const u16* ph = Eh + (size_t)n * 256 + p * 64;
  const u16* pl = El + (size_t)n * 256 + p * 64;
  float s = 0.f;
#pragma unroll
  for (int j = 0; j < 8; ++j) {
    const uint4 hv = *(const uint4*)(ph + j * 8);
    const uint4 lv = *(const uint4*)(pl + j * 8);
    const unsigned hu[4] = {hv.x, hv.y, hv.z, hv.w};
    const unsigned lu[4] = {lv.x, lv.y, lv.z, lv.w};
#pragma unroll
    for (int q = 0; q < 4; ++q) {
      const float v0 = b2f((u16)(hu[q] & 0xffff)) + b2f((u16)(lu[q] & 0xffff));
      const float v1 = b2f((u16)(hu[q] >> 16)) + b2f((u16)(lu[q] >> 16));
      s = fmaf(v0, v0, s);
      s = fmaf(v1, v1, s);
    }
  }
  s += __shfl_xor(s, 1);
  s += __shfl_xor(s, 2);
  if (p == 0) tn[n] = s;
}

// ---------- GRN scale s = 1 + gg*nx from sumsq ----------
__global__ __launch_bounds__(256) void k_grn_scale(const float* __restrict__ GX2,
                                                   const float* __restrict__ gg,
                                                   float* __restrict__ S, int b0) {
  const int b = b0 + blockIdx.x, t = threadIdx.x;
  const float* gxb = GX2 + (size_t)b * 1024;
  float gx[4];
  float s = 0.f;
#pragma unroll
  for (int i = 0; i < 4; ++i) {
    gx[i] = sqrtf(gxb[t + i * 256]);
    s += gx[i];
  }
  const int w = t >> 6, l = t & 63;
#pragma unroll
  for (int o = 32; o > 0; o >>= 1) s += __shfl_down(s, o);
  __shared__ float red[4];
  __shared__ float bc;
  if (l == 0) red[w] = s;
  __syncthreads();
  if (t == 0) bc = 1.0f / ((red[0] + red[1] + red[2] + red[3]) * (1.0f / 1024.0f) + 1e-6f);
  __syncthreads();
  const float inv = bc;
#pragma unroll
  for (int i = 0; i < 4; ++i)
    S[(size_t)b * 1024 + t + i * 256] = fmaf(gg[t + i * 256], gx[i] * inv, 1.0f);
}

// ---------- per-batch scaled W2, split + FRAGMENT order (with pi^-1 on K) ----------
// cid = [colt:1][wcw:1][ks:5][j:2]; lane l elem e: n = colt*128+wcw*64+j*16+(l&15),
// k_label = ks*32+(l>>4)*8+e; orig_k = invpi64(k_label) within its 64-block.
__global__ __launch_bounds__(256) void k_w2prepf(const float* __restrict__ W2,
                                                 const float* __restrict__ S, int b0,
                                                 u16* __restrict__ Wh, u16* __restrict__ Wl) {
  const int bx = blockIdx.x;  // (b-b0)*512 + cid
  const int b = b0 + (bx >> 9);
  const int cid = bx & 511;
  const int colt = cid >> 8, wcw = (cid >> 7) & 1, ks = (cid >> 2) & 31, j = cid & 3;
  const int t = threadIdx.x, l = t & 63, e0 = (t >> 6) * 2;
  const int n = colt * 128 + wcw * 64 + j * 16 + (l & 15);
  const int kl = ks * 32 + (l >> 4) * 8 + e0;
  const size_t ob = (size_t)b * 262144 + (size_t)cid * 512 + l * 8 + e0;
#pragma unroll
  for (int q = 0; q < 2; ++q) {
    const int klq = kl + q;
    const int y = klq & 63;
    const int ko = (klq & ~63) | ((y & 3) << 4) | (y >> 2);  // pi^-1
    const float v = W2[(size_t)ko * 256 + n] * S[(size_t)b * 1024 + ko];
    const u16 h = bfhi(v);
    Wh[ob + q] = h;
    Wl[ob + q] = bfhi(v - b2f(h));
  }
}

// ---------- bias2v = b2 + gb @ W2 (one block per output channel) ----------
__global__ __launch_bounds__(256) void k_bias2(const float* __restrict__ W2,
                                               const float* __restrict__ gb,
                                               const float* __restrict__ b2,
                                               float* __restrict__ out) {
  const int c = blockIdx.x, t = threadIdx.x;
  float acc = 0.f;
#pragma unroll
  for (int j = 0; j < 4; ++j) {
    const int k = t + j * 256;
    acc = fmaf(gb[k], W2[(size_t)k * 256 + c], acc);
  }
  const int w = t >> 6, l = t & 63;
#pragma unroll
  for (int o = 32; o > 0; o >>= 1) acc += __shfl_down(acc, o);
  __shared__ float red[4];
  if (l == 0) red[w] = acc;
  __syncthreads();
  if (t == 0) out[c] = red[0] + red[1] + red[2] + red[3] + b2[c];
}

// ---------- W1^T split + FRAGMENT order ----------
// cid = [colt:3][wcw:1][ks:3][j:2]; lane l elem e: n = colt*128+wcw*64+j*16+(l&15),
// k = ks*32+(l>>4)*8+e  (K of fc1 = LN channels, original order).
__global__ __launch_bounds__(256) void k_wtf(const float* __restrict__ W1,
                                             u16* __restrict__ Wh, u16* __restrict__ Wl) {
  const int bx = blockIdx.x;  // d*512 + cid
  const int d = bx >> 9, cid = bx & 511;
  const int colt = cid >> 6, wcw = (cid >> 5) & 1, ks = (cid >> 2) & 7, j = cid & 3;
  const int t = threadIdx.x, l = t & 63, e0 = (t >> 6) * 2;
  const int n = colt * 128 + wcw * 64 + j * 16 + (l & 15);
  const int k = ks * 32 + (l >> 4) * 8 + e0;
  const float* src = W1 + (size_t)d * 262144;
  const size_t ob = (size_t)bx * 512 + l * 8 + e0;
#pragma unroll
  for (int q = 0; q < 2; ++q) {
    const float v = src[(size_t)(k + q) * 1024 + n];
    const u16 h = bfhi(v);
    Wh[ob + q] = h;
    Wl[ob + q] = bfhi(v - b2f(h));
  }
}

// ---------- codebook split + FRAGMENT order (col = code, k = channel) ----------
__global__ __launch_bounds__(256) void k_csplitf(const float* __restrict__ C,
                                                 u16* __restrict__ Ch, u16* __restrict__ Cl) {
  const int cid = blockIdx.x;  // 512: [colt:3][wcw:1][ks:3][j:2]
  const int colt = cid >> 6, wcw = (cid >> 5) & 1, ks = (cid >> 2) & 7, j = cid & 3;
  const int t = threadIdx.x, l = t & 63, e0 = (t >> 6) * 2;
  const int code = colt * 128 + wcw * 64 + j * 16 + (l & 15);
  const int ch = ks * 32 + (l >> 4) * 8 + e0;
  const size_t ob = (size_t)cid * 512 + l * 8 + e0;
#pragma unroll
  for (int q = 0; q < 2; ++q) {
    const float v = C[(size_t)code * 256 + ch + q];
    const u16 h = bfhi(v);
    Ch[ob + q] = h;
    Cl[ob + q] = bfhi(v - b2f(h));
  }
}

// ---------- numpy-pairwise |c|^2 per code ----------
__device__ __forceinline__ float np_pairwise_sq_256(const float* p) {
  float half[2];
#pragma unroll
  for (int hh = 0; hh < 2; ++hh) {
    float r[8];
#pragma unroll
    for (int j = 0; j < 8; ++j) {
      const float v = p[hh * 128 + j];
      r[j] = __fmul_rn(v, v);
    }
    for (int i = 8; i < 128; i += 8) {
#pragma unroll
      for (int j = 0; j < 8; ++j) {
        const float v = p[hh * 128 + i + j];
        r[j] = __fadd_rn(r[j], __fmul_rn(v, v));
      }
    }
    half[hh] = __fadd_rn(__fadd_rn(__fadd_rn(r[0], r[1]), __fadd_rn(r[2], r[3])),
                         __fadd_rn(__fadd_rn(r[4], r[5]), __fadd_rn(r[6], r[7])));
  }
  return __fadd_rn(half[0], half[1]);
}

__global__ __launch_bounds__(256) void k_c2(const float* __restrict__ cbk, float* __restrict__ c2) {
  const int k = blockIdx.x * 256 + threadIdx.x;
  c2[k] = np_pairwise_sq_256(cbk + (size_t)k * 256);
}

// ---------- index output + quantized gather ----------
__global__ __launch_bounds__(256) void k_idx(const u64* __restrict__ pk, float* __restrict__ outI) {
  const int n = blockIdx.x * 256 + threadIdx.x;
  outI[n] = (float)(unsigned)(pk[n] & 0xffffffffULL);
}

__global__ __launch_bounds__(256) void k_gather(const u64* __restrict__ pk,
                                                const float* __restrict__ cbk,
                                                float* __restrict__ outq) {
  const int t = threadIdx.x;
  const int p0 = blockIdx.x * 64;
  const int b = p0 >> 12, pl = (p0 & 4095) + (t & 63);
  const int cg = t >> 6;
  const int n = p0 + (t & 63);
  const int k = (int)(unsigned)(pk[n] & 0xffffffffULL);
  const float* crow = cbk + (size_t)k * 256 + cg * 64;
  float* ob = outq + (((size_t)(b * 256 + cg * 64)) << 12) + pl;
#pragma unroll 1
  for (int j = 0; j < 16; ++j) {
    const float4 cv = *(const float4*)(crow + j * 4);
    ob[((size_t)(j * 4 + 0)) << 12] = cv.x;
    ob[((size_t)(j * 4 + 1)) << 12] = cv.y;
    ob[((size_t)(j * 4 + 2)) << 12] = cv.z;
    ob[((size_t)(j * 4 + 3)) << 12] = cv.w;
  }
}

extern "C" void kernel_launch(void* const* d_in, const int* in_sizes, int n_in,
                              void* d_out, int out_size, void* d_ws, size_t ws_size,
                              hipStream_t stream) {
  const float* x = (const float*)d_in[0];
  const float* cbk = (const float*)d_in[1];
  const float* Pe[10];
  const float* Pd[10];
  for (int i = 0; i < 10; ++i) Pe[i] = (const float*)d_in[2 + i];
  for (int i = 0; i < 10; ++i) Pd[i] = (const float*)d_in[12 + i];

  float* ws = (float*)d_ws;
  size_t o = 0;
  auto alloc = [&](size_t nf) {
    float* p = ws + o;
    o += (nf + 63) & ~(size_t)63;
    return p;
  };
  float* P1 = alloc(8388608);      // NCHW ping
  u16* Rh = (u16*)alloc(4194304);  // rows hi (also E hi)
  u16* Rl = (u16*)alloc(4194304);  // rows lo (also E lo)
  u16* W1th_e = (u16*)alloc(262144);
  u16* W1tl_e = (u16*)alloc(262144);
  u16* W1th_d = (u16*)alloc(262144);
  u16* W1tl_d = (u16*)alloc(262144);
  u16* W2sh = (u16*)alloc(1048576);
  u16* W2sl = (u16*)alloc(1048576);
  u16* Ch = (u16*)alloc(131072);
  u16* Cl = (u16*)alloc(131072);
  float* C2v = alloc(1024);
  float* GX2 = alloc(8192);
  float* Sv = alloc(8192);
  float* bias2v = alloc(256);
  float* tn = alloc(32768);
  u64* pk = (u64*)alloc(65536);
  const size_t fixedf = o;
  const size_t availf = (ws_size / 4 > fixedf) ? ws_size / 4 - fixedf : 0;
  int chunkB = (int)(availf / 4194304);
  if (chunkB > 8) chunkB = 8;
  if (chunkB < 1) chunkB = 1;
  float* Cv = ws + o;  // conv NCHW fp32, aliases M arena
  u16* Mh = (u16*)(ws + o);
  u16* Ml = (u16*)(ws + o + (size_t)chunkB * 2097152);

  float* outQ = (float*)d_out;
  float* outD = outQ + 8388608;
  float* outI = outD + 8388608;

  auto run_enc = [&](const float* xin, float* xout, u16* Eh, u16* El,
                     const float* const* pp, int d) {
    k_conv<<<2048, 256, 0, stream>>>(xin, pp[0] + (size_t)d * 256 * 49, pp[1] + d * 256, Cv);
    k_lnT<<<1024, 256, 0, stream>>>(Cv, pp[2] + d * 256, pp[3] + d * 256, Rh, Rl, 1);
    k_bias2<<<256, 256, 0, stream>>>(pp[8] + (size_t)d * 262144, pp[7] + d * 1024,
                                     pp[9] + d * 256, bias2v);
    hipMemsetAsync(GX2, 0, 8192 * 4, stream);
    for (int b0 = 0; b0 < 8; b0 += chunkB) {
      const int nb = (8 - b0 < chunkB) ? 8 - b0 : chunkB;
      k_gemm<256, 1, 0, 8><<<dim3(8, nb * 32), 256, 0, stream>>>(
          Rh + (size_t)b0 * 4096 * 256, Rl + (size_t)b0 * 4096 * 256,
          W1th_e + (size_t)d * 262144, W1tl_e + (size_t)d * 262144,
          b0 * 4096, 0, Pe[5] + d * 1024, Mh, Ml, nullptr, nullptr, GX2, nullptr);
      k_grn_scale<<<nb, 256, 0, stream>>>(GX2, pp[6] + d * 1024, Sv, b0);
      k_w2prepf<<<nb * 512, 256, 0, stream>>>(pp[8] + (size_t)d * 262144, Sv, b0, W2sh, W2sl);
      k_gemm<1024, 1, 1, 2><<<dim3(2, nb * 32), 256, 0, stream>>>(
          Mh, Ml, W2sh, W2sl, b0 * 4096, 262144LL, bias2v,
          Eh ? Eh + (size_t)b0 * 4096 * 256 : (u16*)nullptr,
          El ? El + (size_t)b0 * 4096 * 256 : (u16*)nullptr,
          xout, xin, nullptr, nullptr);
    }
  };

  auto run_dec = [&](const float* xin, float* xout, const float* const* pp, int d) {
    k_conv<<<2048, 256, 0, stream>>>(xin, pp[0] + (size_t)d * 256 * 49, pp[1] + d * 256, Cv);
    k_lnT<<<1024, 256, 0, stream>>>(Cv, pp[2] + d * 256, pp[3] + d * 256, Rh, Rl, 0);
    k_bias2<<<256, 256, 0, stream>>>(pp[8] + (size_t)d * 262144, pp[7] + d * 1024,
                                     pp[9] + d * 256, bias2v);
    hipMemsetAsync(GX2, 0, 8192 * 4, stream);
    for (int b0 = 0; b0 < 8; b0 += chunkB) {
      const int nb = (8 - b0 < chunkB) ? 8 - b0 : chunkB;
      k_gemm<256, 0, 0, 8><<<dim3(8, nb * 32), 256, 0, stream>>>(
          Rh + (size_t)b0 * 4096 * 256, nullptr,
          W1th_d + (size_t)d * 262144, nullptr,
          b0 * 4096, 0, Pd[5] + d * 1024, Mh, nullptr, nullptr, nullptr, GX2, nullptr);
      k_grn_scale<<<nb, 256, 0, stream>>>(GX2, pp[6] + d * 1024, Sv, b0);
      k_w2prepf<<<nb * 512, 256, 0, stream>>>(pp[8] + (size_t)d * 262144, Sv, b0, W2sh, W2sl);
      k_gemm<1024, 0, 1, 2><<<dim3(2, nb * 32), 256, 0, stream>>>(
          Mh, nullptr, W2sh, nullptr, b0 * 4096, 262144LL, bias2v,
          nullptr, nullptr, xout, xin, nullptr, nullptr);
    }
  };

  // prep (fragment-ordered B operands)
  k_wtf<<<1024, 256, 0, stream>>>(Pe[4], W1th_e, W1tl_e);
  k_wtf<<<1024, 256, 0, stream>>>(Pd[4], W1th_d, W1tl_d);
  k_csplitf<<<512, 256, 0, stream>>>(cbk, Ch, Cl);
  k_c2<<<4, 256, 0, stream>>>(cbk, C2v);

  // encoder (split-bf16, fused 3-term)
  run_enc(x, P1, nullptr, nullptr, Pe, 0);
  run_enc(P1, nullptr, Rh, Rl, Pe, 1);  // E -> Rh/Rl, no NCHW out

  // VQ
  k_rownorm<<<512, 256, 0, stream>>>(Rh, Rl, tn);
  hipMemsetAsync(pk, 0xFF, 32768 * 8, stream);
  k_gemm<256, 1, 2, 8><<<dim3(8, 256), 256, 0, stream>>>(Rh, Rl, Ch, Cl, 0, 0,
                                                         C2v, nullptr, nullptr, nullptr,
                                                         tn, nullptr, pk);
  k_idx<<<128, 256, 0, stream>>>(pk, outI);
  k_gather<<<512, 256, 0, stream>>>(pk, cbk, outQ);

  // decoder (plain bf16)
  run_dec(outQ, P1, Pd, 0);
  run_dec(P1, outD, Pd, 1);
}

// Round 8
// 858.707 us; speedup vs baseline: 1.1037x; 1.0084x over previous
//
#include <hip/hip_runtime.h>
#include <math.h>
#include <stdint.h>

typedef unsigned short u16;
typedef unsigned long long u64;
typedef __attribute__((ext_vector_type(8))) short bf16x8;
typedef __attribute__((ext_vector_type(4))) float f32x4;

__device__ __forceinline__ u16 bfhi(float v) {
  unsigned u = __float_as_uint(v);
  u += 0x7FFFu + ((u >> 16) & 1u);
  return (u16)(u >> 16);
}
__device__ __forceinline__ float b2f(u16 h) { return __uint_as_float((unsigned)h << 16); }

__device__ __forceinline__ void gload16(void* lds, const void* g) {
  __builtin_amdgcn_global_load_lds(
      (const __attribute__((address_space(1))) unsigned int*)g,
      (__attribute__((address_space(3))) unsigned int*)lds, 16, 0, 0);
}

// ---------- depthwise conv 7x7 + bias: NCHW -> NCHW (coalesced float4 stores) ----------
__global__ __launch_bounds__(256) void k_conv(const float* __restrict__ in,
                                              const float* __restrict__ cw,
                                              const float* __restrict__ cb,
                                              float* __restrict__ out) {
  const int bx = blockIdx.x;  // 8b x 256c
  const int c = bx & 255;
  __shared__ float patch[70 * 76];
  const int t = threadIdx.x;
  const float* plane = in + (size_t)bx * 4096;
  for (int i = t; i < 1330; i += 256) {
    const int row = i / 19, cf = i - row * 19;
    const int bit = (row >> 2) & 1;
    const int gf = cf - 1 - bit;
    const int h = row - 3;
    float4 v = {0.f, 0.f, 0.f, 0.f};
    if ((unsigned)h < 64u && (unsigned)gf < 16u) v = *(const float4*)(plane + h * 64 + gf * 4);
    *(float4*)(patch + row * 76 + cf * 4) = v;
  }
  const float* wp = cw + c * 49;
  float wt[49];
#pragma unroll
  for (int i = 0; i < 49; ++i) wt[i] = wp[i];
  const float bias = cb[c];
  __syncthreads();
  const int j = t & 7, i = t >> 3;
  const int w0 = j * 8, h0 = i * 2;
  float acc[2][8];
#pragma unroll
  for (int dr = 0; dr < 2; ++dr)
#pragma unroll
    for (int ww = 0; ww < 8; ++ww) acc[dr][ww] = bias;
#pragma unroll
  for (int r = 0; r < 8; ++r) {
    const int prow = h0 + r;
    const int bit = (prow >> 2) & 1;
    const float* base = patch + prow * 76 + w0 + 4 * bit;
    float win[16];
#pragma unroll
    for (int q = 0; q < 4; ++q) {
      const float4 v = *(const float4*)(base + q * 4);
      win[q * 4 + 0] = v.x; win[q * 4 + 1] = v.y;
      win[q * 4 + 2] = v.z; win[q * 4 + 3] = v.w;
    }
#pragma unroll
    for (int dr = 0; dr < 2; ++dr) {
      const int kh = r - dr;
      if (kh >= 0 && kh < 7) {
#pragma unroll
        for (int kw = 0; kw < 7; ++kw) {
          const float wv = wt[kh * 7 + kw];
#pragma unroll
          for (int ww = 0; ww < 8; ++ww)
            acc[dr][ww] = fmaf(win[ww + kw + 1], wv, acc[dr][ww]);
        }
      }
    }
  }
  float* op = out + (size_t)bx * 4096;
#pragma unroll
  for (int dr = 0; dr < 2; ++dr) {
    const int hh = h0 + dr;
    float4 o1, o2;
    o1.x = acc[dr][0]; o1.y = acc[dr][1]; o1.z = acc[dr][2]; o1.w = acc[dr][3];
    o2.x = acc[dr][4]; o2.y = acc[dr][5]; o2.z = acc[dr][6]; o2.w = acc[dr][7];
    *(float4*)(op + hh * 64 + w0) = o1;
    *(float4*)(op + hh * 64 + w0 + 4) = o2;
  }
}

// ---------- LN over channels from NCHW, via LDS transpose -> NHWC bf16 hi/lo ----------
__global__ __launch_bounds__(256) void k_lnT(const float* __restrict__ src,
                                             const float* __restrict__ g,
                                             const float* __restrict__ bt,
                                             u16* __restrict__ Rh, u16* __restrict__ Rl,
                                             const int wlo) {
  __shared__ float T[256 * 33];
  __shared__ float red[8 * 32];
  __shared__ float gs[256], bs[256];
  const int t = threadIdx.x;
  const int n0 = blockIdx.x * 32;
  const int b = n0 >> 12, pl = n0 & 4095;
  gs[t] = g[t];
  bs[t] = bt[t];
  const int m = t & 7, h = t >> 3;
  const float* sp = src + (((size_t)(b * 256)) << 12) + pl + m * 4;
#pragma unroll
  for (int it = 0; it < 8; ++it) {
    const int c = it * 32 + h;
    const float4 v = *(const float4*)(sp + ((size_t)c << 12));
    *(float4*)(T + c * 33 + m * 4) = v;
  }
  __syncthreads();
  const int p = t & 31, qq = t >> 5;
  float s = 0.f;
#pragma unroll
  for (int jj = 0; jj < 32; ++jj) s += T[(qq * 32 + jj) * 33 + p];
  red[qq * 32 + p] = s;
  __syncthreads();
  float tot = 0.f;
#pragma unroll
  for (int k = 0; k < 8; ++k) tot += red[k * 32 + p];
  const float mu = tot * (1.0f / 256.0f);
  __syncthreads();
  float s2 = 0.f;
#pragma unroll
  for (int jj = 0; jj < 32; ++jj) {
    const float d = T[(qq * 32 + jj) * 33 + p] - mu;
    s2 = fmaf(d, d, s2);
  }
  red[qq * 32 + p] = s2;
  __syncthreads();
  float tot2 = 0.f;
#pragma unroll
  for (int k = 0; k < 8; ++k) tot2 += red[k * 32 + p];
  const float rs = 1.0f / sqrtf(tot2 * (1.0f / 256.0f) + 1e-5f);
#pragma unroll
  for (int jj = 0; jj < 32; ++jj) {
    const int c = qq * 32 + jj;
    const float y = (T[c * 33 + p] - mu) * rs * gs[c] + bs[c];
    const u16 hh = bfhi(y);
    const u16 ll = bfhi(y - b2f(hh));
    ((unsigned*)T)[c * 33 + p] = ((unsigned)hh << 16) | ll;
  }
  __syncthreads();
  const int w = t >> 6, l = t & 63;
  const unsigned* Tu = (const unsigned*)T;
#pragma unroll
  for (int r = 0; r < 4; ++r) {
    const int px = r * 8 + w * 2 + (l >> 5);
    const int c0 = (l & 31) * 8;
    unsigned hp[4], lp[4];
#pragma unroll
    for (int jj = 0; jj < 4; ++jj) {
      const unsigned a = Tu[(c0 + 2 * jj) * 33 + px];
      const unsigned bb = Tu[(c0 + 2 * jj + 1) * 33 + px];
      hp[jj] = (a >> 16) | (bb & 0xffff0000u);
      lp[jj] = (a & 0xffffu) | (bb << 16);
    }
    const size_t base = (size_t)(n0 + px) * 256 + c0;
    *(uint4*)(Rh + base) = make_uint4(hp[0], hp[1], hp[2], hp[3]);
    if (wlo) *(uint4*)(Rl + base) = make_uint4(lp[0], lp[1], lp[2], lp[3]);
  }
}

// ---------- fused-term MFMA GEMM: C = (Ah+Al) * (Bh+Bl)^T (drop lo*lo) ----------
// A: staged global->LDS (swizzled, conflict-free), 2-phase DOUBLE-buffered for both
//   SPLIT and non-split (R2-verified schedule): ds_read(cur) -> B loads -> stage(next)
//   LAST -> sched_barrier -> MFMA -> __syncthreads. Issue order keeps the stage in
//   flight under the MFMA shadow (in-order vmcnt: bh wait=vmcnt(stage+bl), bl
//   wait=vmcnt(stage) with ~2 MFMA clusters of cover, stage drained at the barrier).
// B: NOT staged -- producers pre-lay B in exact MFMA fragment order; bh/bl read via
//   coalesced global_load_dwordx4 from L2.
// M (EPI=0 output) stored with per-64 K-permutation pi(j*16+lm)=lm*4+j (8B packed
//   stores); w2prepf applies pi^-1.
// Block id remap: XCD = rowt%8, colt fastest -> A-tile L2-resident.
template <int KD, int SPLIT, int EPI, int NCT>
__global__ __launch_bounds__(256) void k_gemm(
    const u16* __restrict__ Ah_, const u16* __restrict__ Al_,
    const u16* __restrict__ Bh_, const u16* __restrict__ Bl_,
    const int row0, const long long bstride,
    const float* __restrict__ pbias,
    u16* __restrict__ poh, u16* __restrict__ pol,
    float* __restrict__ pxout, const float* __restrict__ pxin,
    float* __restrict__ pgx2, u64* __restrict__ pmin) {
  constexpr int ABUF_B = (SPLIT ? 2 : 1) * 8192;  // A slab set: hi [+lo]
  constexpr int STAGE_B = 2 * ABUF_B;             // double-buffered
  constexpr int TRANS_B = (EPI == 1) ? 64 * 129 * 4 : 0;
  constexpr int SMEM_B = STAGE_B > TRANS_B ? STAGE_B : TRANS_B;
  constexpr int NS = KD / 32;
  __shared__ __align__(16) char smem[SMEM_B];

  const int t = threadIdx.x;
  const int w = t >> 6, l = t & 63;
  const int quad = l >> 4, lm = l & 15;
  const int wr = (w & 1) * 64, wc = (w >> 1) * 64;
  const int id = blockIdx.x + gridDim.x * blockIdx.y;
  constexpr int L = (NCT == 8) ? 3 : 1;
  const int colt = (id >> 3) & (NCT - 1);
  const int rowt = (id & 7) + ((id >> (3 + L)) << 3);
  const int nblk0 = rowt * 128;
  const int bglob = (row0 + nblk0) >> 12;

  const u16* Agh = Ah_ + (size_t)nblk0 * KD;
  const u16* Agl = SPLIT ? (Al_ + (size_t)nblk0 * KD) : Ah_;
  // fragment-ordered B base for this wave's column half (wcw = w>>1)
  const size_t bfo = (size_t)bglob * (size_t)bstride +
                     (size_t)((colt * 2 + (w >> 1)) * NS * 4) * 512 + (size_t)l * 8;
  const u16* Bfh = Bh_ + bfo;
  const u16* Bfl = SPLIT ? (Bl_ + bfo) : Bfh;

  f32x4 acc[4][4];
  const f32x4 zz = {0.f, 0.f, 0.f, 0.f};
#pragma unroll
  for (int i = 0; i < 4; ++i)
#pragma unroll
    for (int j = 0; j < 4; ++j) acc[i][j] = zz;

  // stage one 8KB A slab (128 rows x 32 K bf16); LDS linear, source pre-swizzled
  auto stage32 = [&](char* Sp, const u16* Gp, int ks) {
#pragma unroll
    for (int ii = 0; ii < 2; ++ii) {
      const int o = ii * 4096 + t * 16;
      const int row = o >> 6;
      const int lc = ((o >> 4) & 3) ^ ((row >> 1) & 3);
      gload16(Sp + o, Gp + (size_t)row * KD + ks * 32 + lc * 8);
    }
  };
  auto frag_at = [&](const u16* S, int rc) -> bf16x8 {
    const int sw = ((rc >> 1) & 3) ^ quad;
    return *(const bf16x8*)(S + rc * 32 + (sw << 3));
  };

  if constexpr (SPLIT) {
    // double-buffered A (hi+lo), B direct; single barrier per step
    stage32(smem, Agh, 0);
    stage32(smem + 8192, Agl, 0);
    __syncthreads();
#pragma unroll 1
    for (int ks = 0; ks < NS; ++ks) {
      char* base = smem + (size_t)(ks & 1) * ABUF_B;
      bf16x8 ah[4], al[4], bh[4], bl[4];
#pragma unroll
      for (int i = 0; i < 4; ++i) {
        ah[i] = frag_at((const u16*)base, wr + i * 16 + lm);
        al[i] = frag_at((const u16*)(base + 8192), wr + i * 16 + lm);
      }
#pragma unroll
      for (int i = 0; i < 4; ++i) bh[i] = *(const bf16x8*)(Bfh + (ks * 4 + i) * 512);
#pragma unroll
      for (int i = 0; i < 4; ++i) bl[i] = *(const bf16x8*)(Bfl + (ks * 4 + i) * 512);
      if (ks + 1 < NS) {  // stage LAST: stays in flight until the barrier
        char* nb = smem + (size_t)((ks + 1) & 1) * ABUF_B;
        stage32(nb, Agh, ks + 1);
        stage32(nb + 8192, Agl, ks + 1);
      }
      __builtin_amdgcn_sched_barrier(0);  // keep all loads above the MFMA cluster
#pragma unroll
      for (int i = 0; i < 4; ++i)
#pragma unroll
        for (int j = 0; j < 4; ++j)
          acc[i][j] = __builtin_amdgcn_mfma_f32_16x16x32_bf16(ah[i], bh[j], acc[i][j], 0, 0, 0);
#pragma unroll
      for (int i = 0; i < 4; ++i)
#pragma unroll
        for (int j = 0; j < 4; ++j)
          acc[i][j] = __builtin_amdgcn_mfma_f32_16x16x32_bf16(al[i], bh[j], acc[i][j], 0, 0, 0);
#pragma unroll
      for (int i = 0; i < 4; ++i)
#pragma unroll
        for (int j = 0; j < 4; ++j)
          acc[i][j] = __builtin_amdgcn_mfma_f32_16x16x32_bf16(ah[i], bl[j], acc[i][j], 0, 0, 0);
      __syncthreads();  // prefetch lands under MFMA shadow; buffer handoff
    }
  } else {
    // double-buffered A pipeline (verified 2-phase schedule), B direct per step
    stage32(smem, Agh, 0);
    __syncthreads();
#pragma unroll 1
    for (int ks = 0; ks < NS; ++ks) {
      const u16* base = (const u16*)(smem + (size_t)(ks & 1) * ABUF_B);
      bf16x8 ah[4], bh[4];
#pragma unroll
      for (int i = 0; i < 4; ++i) bh[i] = *(const bf16x8*)(Bfh + (ks * 4 + i) * 512);
#pragma unroll
      for (int i = 0; i < 4; ++i) ah[i] = frag_at(base, wr + i * 16 + lm);
      if (ks + 1 < NS) stage32(smem + (size_t)((ks + 1) & 1) * ABUF_B, Agh, ks + 1);
      __builtin_amdgcn_sched_barrier(0);  // keep loads above the MFMA cluster
#pragma unroll
      for (int i = 0; i < 4; ++i)
#pragma unroll
        for (int j = 0; j < 4; ++j)
          acc[i][j] = __builtin_amdgcn_mfma_f32_16x16x32_bf16(ah[i], bh[j], acc[i][j], 0, 0, 0);
      __syncthreads();  // prefetch lands, buffer handoff
    }
  }

  if constexpr (EPI == 0) {
    float csum[4] = {0.f, 0.f, 0.f, 0.f};
    float bv[4];
#pragma unroll
    for (int j = 0; j < 4; ++j) bv[j] = pbias[colt * 128 + wc + j * 16 + lm];
#pragma unroll
    for (int i = 0; i < 4; ++i) {
#pragma unroll
      for (int r = 0; r < 4; ++r) {
        const int row = nblk0 + wr + i * 16 + quad * 4 + r;
        unsigned hp[4], lp[4];
#pragma unroll
        for (int j = 0; j < 4; ++j) {
          const float x = acc[i][j][r] + bv[j];
          const float gl = 0.5f * x * (1.0f + erff(x * 0.70710678118654752f));
          csum[j] = fmaf(gl, gl, csum[j]);
          const u16 h = bfhi(gl);
          hp[j] = h;
          if constexpr (SPLIT) lp[j] = bfhi(gl - b2f(h));
        }
        // pi-packed: 4 cols -> one 8B store at col' = base + lm*4 + j
        const size_t ob = (size_t)row * 1024 + colt * 128 + wc + lm * 4;
        *(uint2*)(poh + ob) = make_uint2(hp[0] | (hp[1] << 16), hp[2] | (hp[3] << 16));
        if constexpr (SPLIT)
          *(uint2*)(pol + ob) = make_uint2(lp[0] | (lp[1] << 16), lp[2] | (lp[3] << 16));
      }
    }
#pragma unroll
    for (int j = 0; j < 4; ++j) {
      float cs = csum[j];
      cs += __shfl_xor(cs, 16);
      cs += __shfl_xor(cs, 32);
      if (quad == 0)
        unsafeAtomicAdd(&pgx2[bglob * 1024 + colt * 128 + wc + j * 16 + lm], cs);
    }
  } else if constexpr (EPI == 1) {
    float* T = (float*)smem;  // [64 cols][pitch 129] f32, per col-half
    const int pg0 = (row0 + nblk0) & 4095;
    const int bb = (row0 + nblk0) >> 12;
#pragma unroll 1
    for (int h = 0; h < 2; ++h) {
      __syncthreads();
      if ((w >> 1) == h) {
#pragma unroll
        for (int i = 0; i < 4; ++i) {
          const int row = wr + i * 16 + quad * 4;
#pragma unroll
          for (int j = 0; j < 4; ++j) {
            const int cl = j * 16 + lm;
#pragma unroll
            for (int r = 0; r < 4; ++r) T[cl * 129 + row + r] = acc[i][j][r];
          }
        }
      }
      __syncthreads();
      const int lp = (l & 31) * 4;
      const int ch2 = l >> 5;
#pragma unroll
      for (int step = 0; step < 8; ++step) {
        const int cl = w * 16 + step * 2 + ch2;
        const int cg = colt * 128 + h * 64 + cl;
        float4 tv = *(float4*)&T[cl * 129 + lp];
        const float bv2 = pbias[cg];
        const size_t nchw = (((size_t)(bb * 256 + cg)) << 12) + pg0 + lp;
        const float4 xv = *(const float4*)(pxin + nchw);
        float4 z;
        z.x = tv.x + bv2 + xv.x;
        z.y = tv.y + bv2 + xv.y;
        z.z = tv.z + bv2 + xv.z;
        z.w = tv.w + bv2 + xv.w;
        if (pxout) *(float4*)(pxout + nchw) = z;
        if (poh) *(float4*)&T[cl * 129 + lp] = z;
      }
      if (poh) {
        __syncthreads();
        // packed E store: 4 cols x u64, bank-safe row map (rows rg+16n)
        const int u = t & 15, c4 = u * 4;
        const int rg = t >> 4;  // 0..15
        const int cg4 = colt * 128 + h * 64 + c4;
#pragma unroll
        for (int n = 0; n < 8; ++n) {
          const int row = rg + 16 * n;
          unsigned hp[4], lp4[4];
#pragma unroll
          for (int q = 0; q < 4; ++q) {
            const float z = T[(c4 + q) * 129 + row];
            const u16 hh = bfhi(z);
            hp[q] = hh;
            lp4[q] = bfhi(z - b2f(hh));
          }
          const size_t idx = (size_t)(nblk0 + row) * 256 + cg4;
          *(uint2*)(poh + idx) = make_uint2(hp[0] | (hp[1] << 16), hp[2] | (hp[3] << 16));
          *(uint2*)(pol + idx) = make_uint2(lp4[0] | (lp4[1] << 16), lp4[2] | (lp4[3] << 16));
        }
      }
    }
  } else {
#pragma unroll
    for (int i = 0; i < 4; ++i) {
#pragma unroll
      for (int r = 0; r < 4; ++r) {
        const int nloc = nblk0 + wr + i * 16 + quad * 4 + r;
        const float tnv = pxin[nloc];
        u64 best = ~0ULL;
#pragma unroll
        for (int j = 0; j < 4; ++j) {
          const int code = colt * 128 + wc + j * 16 + lm;
          const float d = __fadd_rn(__fsub_rn(tnv, __fmul_rn(2.0f, acc[i][j][r])), pbias[code]);
          const u64 pk = (((u64)__float_as_uint(d)) << 32) | (unsigned)code;
          best = pk < best ? pk : best;
        }
#pragma unroll
        for (int off = 1; off < 16; off <<= 1) {
          unsigned lo32 = (unsigned)best, hi32 = (unsigned)(best >> 32);
          lo32 = __shfl_xor(lo32, off);
          hi32 = __shfl_xor(hi32, off);
          const u64 o2 = (((u64)hi32) << 32) | lo32;
          best = o2 < best ? o2 : best;
        }
        if (lm == 0) atomicMin(pmin + nloc, best);
      }
    }
  }
}

// ---------- row sumsq (tn) from bf16 hi/lo E rows ----------
__global__ __launch_bounds__(256) void k_rownorm(const u16* __restrict__ Eh,
                                                 const u16* __restrict__ El,
                                                 float* __restrict__ tn) {
  const int t = threadIdx.x;
  const int r = t >> 2, p = t & 3;
  const int n = blockIdx.x * 64 + r;
  const u16* ph = Eh + (size_t)n * 256 + p * 64;
  const u16* pl = El + (size_t)n * 256 + p * 64;
  float s = 0.f;
#pragma unroll
  for (int j = 0; j < 8; ++j) {
    const uint4 hv = *(const uint4*)(ph + j * 8);
    const uint4 lv = *(const uint4*)(pl + j * 8);
    const unsigned hu[4] = {hv.x, hv.y, hv.z, hv.w};
    const unsigned lu[4] = {lv.x, lv.y, lv.z, lv.w};
#pragma unroll
    for (int q = 0; q < 4; ++q) {
      const float v0 = b2f((u16)(hu[q] & 0xffff)) + b2f((u16)(lu[q] & 0xffff));
      const float v1 = b2f((u16)(hu[q] >> 16)) + b2f((u16)(lu[q] >> 16));
      s = fmaf(v0, v0, s);
      s = fmaf(v1, v1, s);
    }
  }
  s += __shfl_xor(s, 1);
  s += __shfl_xor(s, 2);
  if (p == 0) tn[n] = s;
}

// ---------- GRN scale s = 1 + gg*nx from sumsq ----------
__global__ __launch_bounds__(256) void k_grn_scale(const float* __restrict__ GX2,
                                                   const float* __restrict__ gg,
                                                   float* __restrict__ S, int b0) {
  const int b = b0 + blockIdx.x, t = threadIdx.x;
  const float* gxb = GX2 + (size_t)b * 1024;
  float gx[4];
  float s = 0.f;
#pragma unroll
  for (int i = 0; i < 4; ++i) {
    gx[i] = sqrtf(gxb[t + i * 256]);
    s += gx[i];
  }
  const int w = t >> 6, l = t & 63;
#pragma unroll
  for (int o = 32; o > 0; o >>= 1) s += __shfl_down(s, o);
  __shared__ float red[4];
  __shared__ float bc;
  if (l == 0) red[w] = s;
  __syncthreads();
  if (t == 0) bc = 1.0f / ((red[0] + red[1] + red[2] + red[3]) * (1.0f / 1024.0f) + 1e-6f);
  __syncthreads();
  const float inv = bc;
#pragma unroll
  for (int i = 0; i < 4; ++i)
    S[(size_t)b * 1024 + t + i * 256] = fmaf(gg[t + i * 256], gx[i] * inv, 1.0f);
}

// ---------- per-batch scaled W2, split + FRAGMENT order (with pi^-1 on K) ----------
__global__ __launch_bounds__(256) void k_w2prepf(const float* __restrict__ W2,
                                                 const float* __restrict__ S, int b0,
                                                 u16* __restrict__ Wh, u16* __restrict__ Wl) {
  const int bx = blockIdx.x;  // (b-b0)*512 + cid
  const int b = b0 + (bx >> 9);
  const int cid = bx & 511;
  const int colt = cid >> 8, wcw = (cid >> 7) & 1, ks = (cid >> 2) & 31, j = cid & 3;
  const int t = threadIdx.x, l = t & 63, e0 = (t >> 6) * 2;
  const int n = colt * 128 + wcw * 64 + j * 16 + (l & 15);
  const int kl = ks * 32 + (l >> 4) * 8 + e0;
  const size_t ob = (size_t)b * 262144 + (size_t)cid * 512 + l * 8 + e0;
#pragma unroll
  for (int q = 0; q < 2; ++q) {
    const int klq = kl + q;
    const int y = klq & 63;
    const int ko = (klq & ~63) | ((y & 3) << 4) | (y >> 2);  // pi^-1
    const float v = W2[(size_t)ko * 256 + n] * S[(size_t)b * 1024 + ko];
    const u16 h = bfhi(v);
    Wh[ob + q] = h;
    Wl[ob + q] = bfhi(v - b2f(h));
  }
}

// ---------- bias2v = b2 + gb @ W2 (one block per output channel) ----------
__global__ __launch_bounds__(256) void k_bias2(const float* __restrict__ W2,
                                               const float* __restrict__ gb,
                                               const float* __restrict__ b2,
                                               float* __restrict__ out) {
  const int c = blockIdx.x, t = threadIdx.x;
  float acc = 0.f;
#pragma unroll
  for (int j = 0; j < 4; ++j) {
    const int k = t + j * 256;
    acc = fmaf(gb[k], W2[(size_t)k * 256 + c], acc);
  }
  const int w = t >> 6, l = t & 63;
#pragma unroll
  for (int o = 32; o > 0; o >>= 1) acc += __shfl_down(acc, o);
  __shared__ float red[4];
  if (l == 0) red[w] = acc;
  __syncthreads();
  if (t == 0) out[c] = red[0] + red[1] + red[2] + red[3] + b2[c];
}

// ---------- W1^T split + FRAGMENT order ----------
__global__ __launch_bounds__(256) void k_wtf(const float* __restrict__ W1,
                                             u16* __restrict__ Wh, u16* __restrict__ Wl) {
  const int bx = blockIdx.x;  // d*512 + cid
  const int d = bx >> 9, cid = bx & 511;
  const int colt = cid >> 6, wcw = (cid >> 5) & 1, ks = (cid >> 2) & 7, j = cid & 3;
  const int t = threadIdx.x, l = t & 63, e0 = (t >> 6) * 2;
  const int n = colt * 128 + wcw * 64 + j * 16 + (l & 15);
  const int k = ks * 32 + (l >> 4) * 8 + e0;
  const float* src = W1 + (size_t)d * 262144;
  const size_t ob = (size_t)bx * 512 + l * 8 + e0;
#pragma unroll
  for (int q = 0; q < 2; ++q) {
    const float v = src[(size_t)(k + q) * 1024 + n];
    const u16 h = bfhi(v);
    Wh[ob + q] = h;
    Wl[ob + q] = bfhi(v - b2f(h));
  }
}

// ---------- codebook split + FRAGMENT order (col = code, k = channel) ----------
__global__ __launch_bounds__(256) void k_csplitf(const float* __restrict__ C,
                                                 u16* __restrict__ Ch, u16* __restrict__ Cl) {
  const int cid = blockIdx.x;  // 512: [colt:3][wcw:1][ks:3][j:2]
  const int colt = cid >> 6, wcw = (cid >> 5) & 1, ks = (cid >> 2) & 7, j = cid & 3;
  const int t = threadIdx.x, l = t & 63, e0 = (t >> 6) * 2;
  const int code = colt * 128 + wcw * 64 + j * 16 + (l & 15);
  const int ch = ks * 32 + (l >> 4) * 8 + e0;
  const size_t ob = (size_t)cid * 512 + l * 8 + e0;
#pragma unroll
  for (int q = 0; q < 2; ++q) {
    const float v = C[(size_t)code * 256 + ch + q];
    const u16 h = bfhi(v);
    Ch[ob + q] = h;
    Cl[ob + q] = bfhi(v - b2f(h));
  }
}

// ---------- numpy-pairwise |c|^2 per code ----------
__device__ __forceinline__ float np_pairwise_sq_256(const float* p) {
  float half[2];
#pragma unroll
  for (int hh = 0; hh < 2; ++hh) {
    float r[8];
#pragma unroll
    for (int j = 0; j < 8; ++j) {
      const float v = p[hh * 128 + j];
      r[j] = __fmul_rn(v, v);
    }
    for (int i = 8; i < 128; i += 8) {
#pragma unroll
      for (int j = 0; j < 8; ++j) {
        const float v = p[hh * 128 + i + j];
        r[j] = __fadd_rn(r[j], __fmul_rn(v, v));
      }
    }
    half[hh] = __fadd_rn(__fadd_rn(__fadd_rn(r[0], r[1]), __fadd_rn(r[2], r[3])),
                         __fadd_rn(__fadd_rn(r[4], r[5]), __fadd_rn(r[6], r[7])));
  }
  return __fadd_rn(half[0], half[1]);
}

__global__ __launch_bounds__(256) void k_c2(const float* __restrict__ cbk, float* __restrict__ c2) {
  const int k = blockIdx.x * 256 + threadIdx.x;
  c2[k] = np_pairwise_sq_256(cbk + (size_t)k * 256);
}

// ---------- index output + quantized gather ----------
__global__ __launch_bounds__(256) void k_idx(const u64* __restrict__ pk, float* __restrict__ outI) {
  const int n = blockIdx.x * 256 + threadIdx.x;
  outI[n] = (float)(unsigned)(pk[n] & 0xffffffffULL);
}

__global__ __launch_bounds__(256) void k_gather(const u64* __restrict__ pk,
                                                const float* __restrict__ cbk,
                                                float* __restrict__ outq) {
  const int t = threadIdx.x;
  const int p0 = blockIdx.x * 64;
  const int b = p0 >> 12, pl = (p0 & 4095) + (t & 63);
  const int cg = t >> 6;
  const int n = p0 + (t & 63);
  const int k = (int)(unsigned)(pk[n] & 0xffffffffULL);
  const float* crow = cbk + (size_t)k * 256 + cg * 64;
  float* ob = outq + (((size_t)(b * 256 + cg * 64)) << 12) + pl;
#pragma unroll 1
  for (int j = 0; j < 16; ++j) {
    const float4 cv = *(const float4*)(crow + j * 4);
    ob[((size_t)(j * 4 + 0)) << 12] = cv.x;
    ob[((size_t)(j * 4 + 1)) << 12] = cv.y;
    ob[((size_t)(j * 4 + 2)) << 12] = cv.z;
    ob[((size_t)(j * 4 + 3)) << 12] = cv.w;
  }
}

extern "C" void kernel_launch(void* const* d_in, const int* in_sizes, int n_in,
                              void* d_out, int out_size, void* d_ws, size_t ws_size,
                              hipStream_t stream) {
  const float* x = (const float*)d_in[0];
  const float* cbk = (const float*)d_in[1];
  const float* Pe[10];
  const float* Pd[10];
  for (int i = 0; i < 10; ++i) Pe[i] = (const float*)d_in[2 + i];
  for (int i = 0; i < 10; ++i) Pd[i] = (const float*)d_in[12 + i];

  float* ws = (float*)d_ws;
  size_t o = 0;
  auto alloc = [&](size_t nf) {
    float* p = ws + o;
    o += (nf + 63) & ~(size_t)63;
    return p;
  };
  float* P1 = alloc(8388608);      // NCHW ping
  u16* Rh = (u16*)alloc(4194304);  // rows hi (also E hi)
  u16* Rl = (u16*)alloc(4194304);  // rows lo (also E lo)
  u16* W1th_e = (u16*)alloc(262144);
  u16* W1tl_e = (u16*)alloc(262144);
  u16* W1th_d = (u16*)alloc(262144);
  u16* W1tl_d = (u16*)alloc(262144);
  u16* W2sh = (u16*)alloc(1048576);
  u16* W2sl = (u16*)alloc(1048576);
  u16* Ch = (u16*)alloc(131072);
  u16* Cl = (u16*)alloc(131072);
  float* C2v = alloc(1024);
  float* GX2 = alloc(8192);
  float* Sv = alloc(8192);
  float* bias2v = alloc(256);
  float* tn = alloc(32768);
  u64* pk = (u64*)alloc(65536);
  const size_t fixedf = o;
  const size_t availf = (ws_size / 4 > fixedf) ? ws_size / 4 - fixedf : 0;
  int chunkB = (int)(availf / 4194304);
  if (chunkB > 8) chunkB = 8;
  if (chunkB < 1) chunkB = 1;
  float* Cv = ws + o;  // conv NCHW fp32, aliases M arena
  u16* Mh = (u16*)(ws + o);
  u16* Ml = (u16*)(ws + o + (size_t)chunkB * 2097152);

  float* outQ = (float*)d_out;
  float* outD = outQ + 8388608;
  float* outI = outD + 8388608;

  auto run_enc = [&](const float* xin, float* xout, u16* Eh, u16* El,
                     const float* const* pp, int d) {
    k_conv<<<2048, 256, 0, stream>>>(xin, pp[0] + (size_t)d * 256 * 49, pp[1] + d * 256, Cv);
    k_lnT<<<1024, 256, 0, stream>>>(Cv, pp[2] + d * 256, pp[3] + d * 256, Rh, Rl, 1);
    k_bias2<<<256, 256, 0, stream>>>(pp[8] + (size_t)d * 262144, pp[7] + d * 1024,
                                     pp[9] + d * 256, bias2v);
    hipMemsetAsync(GX2, 0, 8192 * 4, stream);
    for (int b0 = 0; b0 < 8; b0 += chunkB) {
      const int nb = (8 - b0 < chunkB) ? 8 - b0 : chunkB;
      k_gemm<256, 1, 0, 8><<<dim3(8, nb * 32), 256, 0, stream>>>(
          Rh + (size_t)b0 * 4096 * 256, Rl + (size_t)b0 * 4096 * 256,
          W1th_e + (size_t)d * 262144, W1tl_e + (size_t)d * 262144,
          b0 * 4096, 0, Pe[5] + d * 1024, Mh, Ml, nullptr, nullptr, GX2, nullptr);
      k_grn_scale<<<nb, 256, 0, stream>>>(GX2, pp[6] + d * 1024, Sv, b0);
      k_w2prepf<<<nb * 512, 256, 0, stream>>>(pp[8] + (size_t)d * 262144, Sv, b0, W2sh, W2sl);
      k_gemm<1024, 1, 1, 2><<<dim3(2, nb * 32), 256, 0, stream>>>(
          Mh, Ml, W2sh, W2sl, b0 * 4096, 262144LL, bias2v,
          Eh ? Eh + (size_t)b0 * 4096 * 256 : (u16*)nullptr,
          El ? El + (size_t)b0 * 4096 * 256 : (u16*)nullptr,
          xout, xin, nullptr, nullptr);
    }
  };

  auto run_dec = [&](const float* xin, float* xout, const float* const* pp, int d) {
    k_conv<<<2048, 256, 0, stream>>>(xin, pp[0] + (size_t)d * 256 * 49, pp[1] + d * 256, Cv);
    k_lnT<<<1024, 256, 0, stream>>>(Cv, pp[2] + d * 256, pp[3] + d * 256, Rh, Rl, 0);
    k_bias2<<<256, 256, 0, stream>>>(pp[8] + (size_t)d * 262144, pp[7] + d * 1024,
                                     pp[9] + d * 256, bias2v);
    hipMemsetAsync(GX2, 0, 8192 * 4, stream);
    for (int b0 = 0; b0 < 8; b0 += chunkB) {
      const int nb = (8 - b0 < chunkB) ? 8 - b0 : chunkB;
      k_gemm<256, 0, 0, 8><<<dim3(8, nb * 32), 256, 0, stream>>>(
          Rh + (size_t)b0 * 4096 * 256, nullptr,
          W1th_d + (size_t)d * 262144, nullptr,
          b0 * 4096, 0, Pd[5] + d * 1024, Mh, nullptr, nullptr, nullptr, GX2, nullptr);
      k_grn_scale<<<nb, 256, 0, stream>>>(GX2, pp[6] + d * 1024, Sv, b0);
      k_w2prepf<<<nb * 512, 256, 0, stream>>>(pp[8] + (size_t)d * 262144, Sv, b0, W2sh, W2sl);
      k_gemm<1024, 0, 1, 2><<<dim3(2, nb * 32), 256, 0, stream>>>(
          Mh, nullptr, W2sh, nullptr, b0 * 4096, 262144LL, bias2v,
          nullptr, nullptr, xout, xin, nullptr, nullptr);
    }
  };

  // prep (fragment-ordered B operands)
  k_wtf<<<1024, 256, 0, stream>>>(Pe[4], W1th_e, W1tl_e);
  k_wtf<<<1024, 256, 0, stream>>>(Pd[4], W1th_d, W1tl_d);
  k_csplitf<<<512, 256, 0, stream>>>(cbk, Ch, Cl);
  k_c2<<<4, 256, 0, stream>>>(cbk, C2v);

  // encoder (split-bf16, fused 3-term)
  run_enc(x, P1, nullptr, nullptr, Pe, 0);
  run_enc(P1, nullptr, Rh, Rl, Pe, 1);  // E -> Rh/Rl, no NCHW out

  // VQ
  k_rownorm<<<512, 256, 0, stream>>>(Rh, Rl, tn);
  hipMemsetAsync(pk, 0xFF, 32768 * 8, stream);
  k_gemm<256, 1, 2, 8><<<dim3(8, 256), 256, 0, stream>>>(Rh, Rl, Ch, Cl, 0, 0,
                                                         C2v, nullptr, nullptr, nullptr,
                                                         tn, nullptr, pk);
  k_idx<<<128, 256, 0, stream>>>(pk, outI);
  k_gather<<<512, 256, 0, stream>>>(pk, cbk, outQ);

  // decoder (plain bf16)
  run_dec(outQ, P1, Pd, 0);
  run_dec(P1, outD, Pd, 1);
}

// Round 9
// 810.138 us; speedup vs baseline: 1.1699x; 1.0600x over previous
//
#include <hip/hip_runtime.h>
#include <math.h>
#include <stdint.h>

typedef unsigned short u16;
typedef unsigned long long u64;
typedef __attribute__((ext_vector_type(8))) short bf16x8;
typedef __attribute__((ext_vector_type(4))) float f32x4;

__device__ __forceinline__ u16 bfhi(float v) {
  unsigned u = __float_as_uint(v);
  u += 0x7FFFu + ((u >> 16) & 1u);
  return (u16)(u >> 16);
}
__device__ __forceinline__ float b2f(u16 h) { return __uint_as_float((unsigned)h << 16); }

__device__ __forceinline__ void gload16(void* lds, const void* g) {
  __builtin_amdgcn_global_load_lds(
      (const __attribute__((address_space(1))) unsigned int*)g,
      (__attribute__((address_space(3))) unsigned int*)lds, 16, 0, 0);
}

// exact-erf GELU via Abramowitz-Stegun 7.1.26 (|erf err| <= 1.5e-7, branch-free)
// ~16 VALU vs ~50 for libm erff (which executes both divergent branches per wave).
__device__ __forceinline__ float gelu_erf(float x) {
  const float z = fabsf(x) * 0.70710678118654752f;
  const float t = __builtin_amdgcn_rcpf(fmaf(0.3275911f, z, 1.0f));
  float p = fmaf(1.061405429f, t, -1.453152027f);
  p = fmaf(p, t, 1.421413741f);
  p = fmaf(p, t, -0.284496736f);
  p = fmaf(p, t, 0.254829592f);
  p *= t;
  const float E = p * __expf(-z * z);  // erfc(z), z >= 0 (no cancellation)
  const float hxE = 0.5f * x * E;
  return x >= 0.f ? x - hxE : hxE;
}

// ---------- depthwise conv 7x7 + bias: NCHW -> NCHW (coalesced float4 stores) ----------
__global__ __launch_bounds__(256) void k_conv(const float* __restrict__ in,
                                              const float* __restrict__ cw,
                                              const float* __restrict__ cb,
                                              float* __restrict__ out) {
  const int bx = blockIdx.x;  // 8b x 256c
  const int c = bx & 255;
  __shared__ float patch[70 * 76];
  const int t = threadIdx.x;
  const float* plane = in + (size_t)bx * 4096;
  for (int i = t; i < 1330; i += 256) {
    const int row = i / 19, cf = i - row * 19;
    const int bit = (row >> 2) & 1;
    const int gf = cf - 1 - bit;
    const int h = row - 3;
    float4 v = {0.f, 0.f, 0.f, 0.f};
    if ((unsigned)h < 64u && (unsigned)gf < 16u) v = *(const float4*)(plane + h * 64 + gf * 4);
    *(float4*)(patch + row * 76 + cf * 4) = v;
  }
  const float* wp = cw + c * 49;
  float wt[49];
#pragma unroll
  for (int i = 0; i < 49; ++i) wt[i] = wp[i];
  const float bias = cb[c];
  __syncthreads();
  const int j = t & 7, i = t >> 3;
  const int w0 = j * 8, h0 = i * 2;
  float acc[2][8];
#pragma unroll
  for (int dr = 0; dr < 2; ++dr)
#pragma unroll
    for (int ww = 0; ww < 8; ++ww) acc[dr][ww] = bias;
#pragma unroll
  for (int r = 0; r < 8; ++r) {
    const int prow = h0 + r;
    const int bit = (prow >> 2) & 1;
    const float* base = patch + prow * 76 + w0 + 4 * bit;
    float win[16];
#pragma unroll
    for (int q = 0; q < 4; ++q) {
      const float4 v = *(const float4*)(base + q * 4);
      win[q * 4 + 0] = v.x; win[q * 4 + 1] = v.y;
      win[q * 4 + 2] = v.z; win[q * 4 + 3] = v.w;
    }
#pragma unroll
    for (int dr = 0; dr < 2; ++dr) {
      const int kh = r - dr;
      if (kh >= 0 && kh < 7) {
#pragma unroll
        for (int kw = 0; kw < 7; ++kw) {
          const float wv = wt[kh * 7 + kw];
#pragma unroll
          for (int ww = 0; ww < 8; ++ww)
            acc[dr][ww] = fmaf(win[ww + kw + 1], wv, acc[dr][ww]);
        }
      }
    }
  }
  float* op = out + (size_t)bx * 4096;
#pragma unroll
  for (int dr = 0; dr < 2; ++dr) {
    const int hh = h0 + dr;
    float4 o1, o2;
    o1.x = acc[dr][0]; o1.y = acc[dr][1]; o1.z = acc[dr][2]; o1.w = acc[dr][3];
    o2.x = acc[dr][4]; o2.y = acc[dr][5]; o2.z = acc[dr][6]; o2.w = acc[dr][7];
    *(float4*)(op + hh * 64 + w0) = o1;
    *(float4*)(op + hh * 64 + w0 + 4) = o2;
  }
}

// ---------- LN over channels from NCHW, via LDS transpose -> NHWC bf16 hi/lo ----------
__global__ __launch_bounds__(256) void k_lnT(const float* __restrict__ src,
                                             const float* __restrict__ g,
                                             const float* __restrict__ bt,
                                             u16* __restrict__ Rh, u16* __restrict__ Rl,
                                             const int wlo) {
  __shared__ float T[256 * 33];
  __shared__ float red[8 * 32];
  __shared__ float gs[256], bs[256];
  const int t = threadIdx.x;
  const int n0 = blockIdx.x * 32;
  const int b = n0 >> 12, pl = n0 & 4095;
  gs[t] = g[t];
  bs[t] = bt[t];
  const int m = t & 7, h = t >> 3;
  const float* sp = src + (((size_t)(b * 256)) << 12) + pl + m * 4;
#pragma unroll
  for (int it = 0; it < 8; ++it) {
    const int c = it * 32 + h;
    const float4 v = *(const float4*)(sp + ((size_t)c << 12));
    *(float4*)(T + c * 33 + m * 4) = v;
  }
  __syncthreads();
  const int p = t & 31, qq = t >> 5;
  float s = 0.f;
#pragma unroll
  for (int jj = 0; jj < 32; ++jj) s += T[(qq * 32 + jj) * 33 + p];
  red[qq * 32 + p] = s;
  __syncthreads();
  float tot = 0.f;
#pragma unroll
  for (int k = 0; k < 8; ++k) tot += red[k * 32 + p];
  const float mu = tot * (1.0f / 256.0f);
  __syncthreads();
  float s2 = 0.f;
#pragma unroll
  for (int jj = 0; jj < 32; ++jj) {
    const float d = T[(qq * 32 + jj) * 33 + p] - mu;
    s2 = fmaf(d, d, s2);
  }
  red[qq * 32 + p] = s2;
  __syncthreads();
  float tot2 = 0.f;
#pragma unroll
  for (int k = 0; k < 8; ++k) tot2 += red[k * 32 + p];
  const float rs = 1.0f / sqrtf(tot2 * (1.0f / 256.0f) + 1e-5f);
#pragma unroll
  for (int jj = 0; jj < 32; ++jj) {
    const int c = qq * 32 + jj;
    const float y = (T[c * 33 + p] - mu) * rs * gs[c] + bs[c];
    const u16 hh = bfhi(y);
    const u16 ll = bfhi(y - b2f(hh));
    ((unsigned*)T)[c * 33 + p] = ((unsigned)hh << 16) | ll;
  }
  __syncthreads();
  const int w = t >> 6, l = t & 63;
  const unsigned* Tu = (const unsigned*)T;
#pragma unroll
  for (int r = 0; r < 4; ++r) {
    const int px = r * 8 + w * 2 + (l >> 5);
    const int c0 = (l & 31) * 8;
    unsigned hp[4], lp[4];
#pragma unroll
    for (int jj = 0; jj < 4; ++jj) {
      const unsigned a = Tu[(c0 + 2 * jj) * 33 + px];
      const unsigned bb = Tu[(c0 + 2 * jj + 1) * 33 + px];
      hp[jj] = (a >> 16) | (bb & 0xffff0000u);
      lp[jj] = (a & 0xffffu) | (bb << 16);
    }
    const size_t base = (size_t)(n0 + px) * 256 + c0;
    *(uint4*)(Rh + base) = make_uint4(hp[0], hp[1], hp[2], hp[3]);
    if (wlo) *(uint4*)(Rl + base) = make_uint4(lp[0], lp[1], lp[2], lp[3]);
  }
}

// ---------- fused-term MFMA GEMM: C = (Ah+Al) * (Bh+Bl)^T (drop lo*lo) ----------
// A: staged global->LDS (swizzled, conflict-free), 2-phase DOUBLE-buffered for both
//   SPLIT and non-split (R2-verified schedule): ds_read(cur) -> B loads -> stage(next)
//   LAST -> sched_barrier -> MFMA -> __syncthreads.
// B: NOT staged -- producers pre-lay B in exact MFMA fragment order; bh/bl read via
//   coalesced global_load_dwordx4 from L2.
// M (EPI=0 output) stored with per-64 K-permutation pi(j*16+lm)=lm*4+j (8B packed
//   stores); w2prepf applies pi^-1.
// Block id remap: XCD = rowt%8, colt fastest -> A-tile L2-resident.
template <int KD, int SPLIT, int EPI, int NCT>
__global__ __launch_bounds__(256) void k_gemm(
    const u16* __restrict__ Ah_, const u16* __restrict__ Al_,
    const u16* __restrict__ Bh_, const u16* __restrict__ Bl_,
    const int row0, const long long bstride,
    const float* __restrict__ pbias,
    u16* __restrict__ poh, u16* __restrict__ pol,
    float* __restrict__ pxout, const float* __restrict__ pxin,
    float* __restrict__ pgx2, u64* __restrict__ pmin) {
  constexpr int ABUF_B = (SPLIT ? 2 : 1) * 8192;  // A slab set: hi [+lo]
  constexpr int STAGE_B = 2 * ABUF_B;             // double-buffered
  constexpr int TRANS_B = (EPI == 1) ? 64 * 129 * 4 : 0;
  constexpr int SMEM_B = STAGE_B > TRANS_B ? STAGE_B : TRANS_B;
  constexpr int NS = KD / 32;
  __shared__ __align__(16) char smem[SMEM_B];

  const int t = threadIdx.x;
  const int w = t >> 6, l = t & 63;
  const int quad = l >> 4, lm = l & 15;
  const int wr = (w & 1) * 64, wc = (w >> 1) * 64;
  const int id = blockIdx.x + gridDim.x * blockIdx.y;
  constexpr int L = (NCT == 8) ? 3 : 1;
  const int colt = (id >> 3) & (NCT - 1);
  const int rowt = (id & 7) + ((id >> (3 + L)) << 3);
  const int nblk0 = rowt * 128;
  const int bglob = (row0 + nblk0) >> 12;

  const u16* Agh = Ah_ + (size_t)nblk0 * KD;
  const u16* Agl = SPLIT ? (Al_ + (size_t)nblk0 * KD) : Ah_;
  // fragment-ordered B base for this wave's column half (wcw = w>>1)
  const size_t bfo = (size_t)bglob * (size_t)bstride +
                     (size_t)((colt * 2 + (w >> 1)) * NS * 4) * 512 + (size_t)l * 8;
  const u16* Bfh = Bh_ + bfo;
  const u16* Bfl = SPLIT ? (Bl_ + bfo) : Bfh;

  f32x4 acc[4][4];
  const f32x4 zz = {0.f, 0.f, 0.f, 0.f};
#pragma unroll
  for (int i = 0; i < 4; ++i)
#pragma unroll
    for (int j = 0; j < 4; ++j) acc[i][j] = zz;

  // stage one 8KB A slab (128 rows x 32 K bf16); LDS linear, source pre-swizzled
  auto stage32 = [&](char* Sp, const u16* Gp, int ks) {
#pragma unroll
    for (int ii = 0; ii < 2; ++ii) {
      const int o = ii * 4096 + t * 16;
      const int row = o >> 6;
      const int lc = ((o >> 4) & 3) ^ ((row >> 1) & 3);
      gload16(Sp + o, Gp + (size_t)row * KD + ks * 32 + lc * 8);
    }
  };
  auto frag_at = [&](const u16* S, int rc) -> bf16x8 {
    const int sw = ((rc >> 1) & 3) ^ quad;
    return *(const bf16x8*)(S + rc * 32 + (sw << 3));
  };

  if constexpr (SPLIT) {
    // double-buffered A (hi+lo), B direct; single barrier per step
    stage32(smem, Agh, 0);
    stage32(smem + 8192, Agl, 0);
    __syncthreads();
#pragma unroll 1
    for (int ks = 0; ks < NS; ++ks) {
      char* base = smem + (size_t)(ks & 1) * ABUF_B;
      bf16x8 ah[4], al[4], bh[4], bl[4];
#pragma unroll
      for (int i = 0; i < 4; ++i) {
        ah[i] = frag_at((const u16*)base, wr + i * 16 + lm);
        al[i] = frag_at((const u16*)(base + 8192), wr + i * 16 + lm);
      }
#pragma unroll
      for (int i = 0; i < 4; ++i) bh[i] = *(const bf16x8*)(Bfh + (ks * 4 + i) * 512);
#pragma unroll
      for (int i = 0; i < 4; ++i) bl[i] = *(const bf16x8*)(Bfl + (ks * 4 + i) * 512);
      if (ks + 1 < NS) {  // stage LAST: stays in flight until the barrier
        char* nb = smem + (size_t)((ks + 1) & 1) * ABUF_B;
        stage32(nb, Agh, ks + 1);
        stage32(nb + 8192, Agl, ks + 1);
      }
      __builtin_amdgcn_sched_barrier(0);  // keep all loads above the MFMA cluster
#pragma unroll
      for (int i = 0; i < 4; ++i)
#pragma unroll
        for (int j = 0; j < 4; ++j)
          acc[i][j] = __builtin_amdgcn_mfma_f32_16x16x32_bf16(ah[i], bh[j], acc[i][j], 0, 0, 0);
#pragma unroll
      for (int i = 0; i < 4; ++i)
#pragma unroll
        for (int j = 0; j < 4; ++j)
          acc[i][j] = __builtin_amdgcn_mfma_f32_16x16x32_bf16(al[i], bh[j], acc[i][j], 0, 0, 0);
#pragma unroll
      for (int i = 0; i < 4; ++i)
#pragma unroll
        for (int j = 0; j < 4; ++j)
          acc[i][j] = __builtin_amdgcn_mfma_f32_16x16x32_bf16(ah[i], bl[j], acc[i][j], 0, 0, 0);
      __syncthreads();  // prefetch lands under MFMA shadow; buffer handoff
    }
  } else {
    // double-buffered A pipeline (verified 2-phase schedule), B direct per step
    stage32(smem, Agh, 0);
    __syncthreads();
#pragma unroll 1
    for (int ks = 0; ks < NS; ++ks) {
      const u16* base = (const u16*)(smem + (size_t)(ks & 1) * ABUF_B);
      bf16x8 ah[4], bh[4];
#pragma unroll
      for (int i = 0; i < 4; ++i) bh[i] = *(const bf16x8*)(Bfh + (ks * 4 + i) * 512);
#pragma unroll
      for (int i = 0; i < 4; ++i) ah[i] = frag_at(base, wr + i * 16 + lm);
      if (ks + 1 < NS) stage32(smem + (size_t)((ks + 1) & 1) * ABUF_B, Agh, ks + 1);
      __builtin_amdgcn_sched_barrier(0);  // keep loads above the MFMA cluster
#pragma unroll
      for (int i = 0; i < 4; ++i)
#pragma unroll
        for (int j = 0; j < 4; ++j)
          acc[i][j] = __builtin_amdgcn_mfma_f32_16x16x32_bf16(ah[i], bh[j], acc[i][j], 0, 0, 0);
      __syncthreads();  // prefetch lands, buffer handoff
    }
  }

  if constexpr (EPI == 0) {
    float csum[4] = {0.f, 0.f, 0.f, 0.f};
    float bv[4];
#pragma unroll
    for (int j = 0; j < 4; ++j) bv[j] = pbias[colt * 128 + wc + j * 16 + lm];
#pragma unroll
    for (int i = 0; i < 4; ++i) {
#pragma unroll
      for (int r = 0; r < 4; ++r) {
        const int row = nblk0 + wr + i * 16 + quad * 4 + r;
        unsigned hp[4], lp[4];
#pragma unroll
        for (int j = 0; j < 4; ++j) {
          const float x = acc[i][j][r] + bv[j];
          const float gl = gelu_erf(x);
          csum[j] = fmaf(gl, gl, csum[j]);
          const u16 h = bfhi(gl);
          hp[j] = h;
          if constexpr (SPLIT) lp[j] = bfhi(gl - b2f(h));
        }
        // pi-packed: 4 cols -> one 8B store at col' = base + lm*4 + j
        const size_t ob = (size_t)row * 1024 + colt * 128 + wc + lm * 4;
        *(uint2*)(poh + ob) = make_uint2(hp[0] | (hp[1] << 16), hp[2] | (hp[3] << 16));
        if constexpr (SPLIT)
          *(uint2*)(pol + ob) = make_uint2(lp[0] | (lp[1] << 16), lp[2] | (lp[3] << 16));
      }
    }
#pragma unroll
    for (int j = 0; j < 4; ++j) {
      float cs = csum[j];
      cs += __shfl_xor(cs, 16);
      cs += __shfl_xor(cs, 32);
      if (quad == 0)
        unsafeAtomicAdd(&pgx2[bglob * 1024 + colt * 128 + wc + j * 16 + lm], cs);
    }
  } else if constexpr (EPI == 1) {
    float* T = (float*)smem;  // [64 cols][pitch 129] f32, per col-half
    const int pg0 = (row0 + nblk0) & 4095;
    const int bb = (row0 + nblk0) >> 12;
#pragma unroll 1
    for (int h = 0; h < 2; ++h) {
      __syncthreads();
      if ((w >> 1) == h) {
#pragma unroll
        for (int i = 0; i < 4; ++i) {
          const int row = wr + i * 16 + quad * 4;
#pragma unroll
          for (int j = 0; j < 4; ++j) {
            const int cl = j * 16 + lm;
#pragma unroll
            for (int r = 0; r < 4; ++r) T[cl * 129 + row + r] = acc[i][j][r];
          }
        }
      }
      __syncthreads();
      const int lp = (l & 31) * 4;
      const int ch2 = l >> 5;
#pragma unroll
      for (int step = 0; step < 8; ++step) {
        const int cl = w * 16 + step * 2 + ch2;
        const int cg = colt * 128 + h * 64 + cl;
        float4 tv = *(float4*)&T[cl * 129 + lp];
        const float bv2 = pbias[cg];
        const size_t nchw = (((size_t)(bb * 256 + cg)) << 12) + pg0 + lp;
        const float4 xv = *(const float4*)(pxin + nchw);
        float4 z;
        z.x = tv.x + bv2 + xv.x;
        z.y = tv.y + bv2 + xv.y;
        z.z = tv.z + bv2 + xv.z;
        z.w = tv.w + bv2 + xv.w;
        if (pxout) *(float4*)(pxout + nchw) = z;
        if (poh) *(float4*)&T[cl * 129 + lp] = z;
      }
      if (poh) {
        __syncthreads();
        // packed E store: 4 cols x u64, bank-safe row map (rows rg+16n)
        const int u = t & 15, c4 = u * 4;
        const int rg = t >> 4;  // 0..15
        const int cg4 = colt * 128 + h * 64 + c4;
#pragma unroll
        for (int n = 0; n < 8; ++n) {
          const int row = rg + 16 * n;
          unsigned hp[4], lp4[4];
#pragma unroll
          for (int q = 0; q < 4; ++q) {
            const float z = T[(c4 + q) * 129 + row];
            const u16 hh = bfhi(z);
            hp[q] = hh;
            lp4[q] = bfhi(z - b2f(hh));
          }
          const size_t idx = (size_t)(nblk0 + row) * 256 + cg4;
          *(uint2*)(poh + idx) = make_uint2(hp[0] | (hp[1] << 16), hp[2] | (hp[3] << 16));
          *(uint2*)(pol + idx) = make_uint2(lp4[0] | (lp4[1] << 16), lp4[2] | (lp4[3] << 16));
        }
      }
    }
  } else {
#pragma unroll
    for (int i = 0; i < 4; ++i) {
#pragma unroll
      for (int r = 0; r < 4; ++r) {
        const int nloc = nblk0 + wr + i * 16 + quad * 4 + r;
        const float tnv = pxin[nloc];
        u64 best = ~0ULL;
#pragma unroll
        for (int j = 0; j < 4; ++j) {
          const int code = colt * 128 + wc + j * 16 + lm;
          const float d = __fadd_rn(__fsub_rn(tnv, __fmul_rn(2.0f, acc[i][j][r])), pbias[code]);
          const u64 pk = (((u64)__float_as_uint(d)) << 32) | (unsigned)code;
          best = pk < best ? pk : best;
        }
#pragma unroll
        for (int off = 1; off < 16; off <<= 1) {
          unsigned lo32 = (unsigned)best, hi32 = (unsigned)(best >> 32);
          lo32 = __shfl_xor(lo32, off);
          hi32 = __shfl_xor(hi32, off);
          const u64 o2 = (((u64)hi32) << 32) | lo32;
          best = o2 < best ? o2 : best;
        }
        if (lm == 0) atomicMin(pmin + nloc, best);
      }
    }
  }
}

// ---------- row sumsq (tn) from bf16 hi/lo E rows ----------
__global__ __launch_bounds__(256) void k_rownorm(const u16* __restrict__ Eh,
                                                 const u16* __restrict__ El,
                                                 float* __restrict__ tn) {
  const int t = threadIdx.x;
  const int r = t >> 2, p = t & 3;
  const int n = blockIdx.x * 64 + r;
  const u16* ph = Eh + (size_t)n * 256 + p * 64;
  const u16* pl = El + (size_t)n * 256 + p * 64;
  float s = 0.f;
#pragma unroll
  for (int j = 0; j < 8; ++j) {
    const uint4 hv = *(const uint4*)(ph + j * 8);
    const uint4 lv = *(const uint4*)(pl + j * 8);
    const unsigned hu[4] = {hv.x, hv.y, hv.z, hv.w};
    const unsigned lu[4] = {lv.x, lv.y, lv.z, lv.w};
#pragma unroll
    for (int q = 0; q < 4; ++q) {
      const float v0 = b2f((u16)(hu[q] & 0xffff)) + b2f((u16)(lu[q] & 0xffff));
      const float v1 = b2f((u16)(hu[q] >> 16)) + b2f((u16)(lu[q] >> 16));
      s = fmaf(v0, v0, s);
      s = fmaf(v1, v1, s);
    }
  }
  s += __shfl_xor(s, 1);
  s += __shfl_xor(s, 2);
  if (p == 0) tn[n] = s;
}

// ---------- GRN scale s = 1 + gg*nx from sumsq ----------
__global__ __launch_bounds__(256) void k_grn_scale(const float* __restrict__ GX2,
                                                   const float* __restrict__ gg,
                                                   float* __restrict__ S, int b0) {
  const int b = b0 + blockIdx.x, t = threadIdx.x;
  const float* gxb = GX2 + (size_t)b * 1024;
  float gx[4];
  float s = 0.f;
#pragma unroll
  for (int i = 0; i < 4; ++i) {
    gx[i] = sqrtf(gxb[t + i * 256]);
    s += gx[i];
  }
  const int w = t >> 6, l = t & 63;
#pragma unroll
  for (int o = 32; o > 0; o >>= 1) s += __shfl_down(s, o);
  __shared__ float red[4];
  __shared__ float bc;
  if (l == 0) red[w] = s;
  __syncthreads();
  if (t == 0) bc = 1.0f / ((red[0] + red[1] + red[2] + red[3]) * (1.0f / 1024.0f) + 1e-6f);
  __syncthreads();
  const float inv = bc;
#pragma unroll
  for (int i = 0; i < 4; ++i)
    S[(size_t)b * 1024 + t + i * 256] = fmaf(gg[t + i * 256], gx[i] * inv, 1.0f);
}

// ---------- per-batch scaled W2, split + FRAGMENT order (with pi^-1 on K) ----------
__global__ __launch_bounds__(256) void k_w2prepf(const float* __restrict__ W2,
                                                 const float* __restrict__ S, int b0,
                                                 u16* __restrict__ Wh, u16* __restrict__ Wl) {
  const int bx = blockIdx.x;  // (b-b0)*512 + cid
  const int b = b0 + (bx >> 9);
  const int cid = bx & 511;
  const int colt = cid >> 8, wcw = (cid >> 7) & 1, ks = (cid >> 2) & 31, j = cid & 3;
  const int t = threadIdx.x, l = t & 63, e0 = (t >> 6) * 2;
  const int n = colt * 128 + wcw * 64 + j * 16 + (l & 15);
  const int kl = ks * 32 + (l >> 4) * 8 + e0;
  const size_t ob = (size_t)b * 262144 + (size_t)cid * 512 + l * 8 + e0;
#pragma unroll
  for (int q = 0; q < 2; ++q) {
    const int klq = kl + q;
    const int y = klq & 63;
    const int ko = (klq & ~63) | ((y & 3) << 4) | (y >> 2);  // pi^-1
    const float v = W2[(size_t)ko * 256 + n] * S[(size_t)b * 1024 + ko];
    const u16 h = bfhi(v);
    Wh[ob + q] = h;
    Wl[ob + q] = bfhi(v - b2f(h));
  }
}

// ---------- bias2v = b2 + gb @ W2 (one block per output channel) ----------
__global__ __launch_bounds__(256) void k_bias2(const float* __restrict__ W2,
                                               const float* __restrict__ gb,
                                               const float* __restrict__ b2,
                                               float* __restrict__ out) {
  const int c = blockIdx.x, t = threadIdx.x;
  float acc = 0.f;
#pragma unroll
  for (int j = 0; j < 4; ++j) {
    const int k = t + j * 256;
    acc = fmaf(gb[k], W2[(size_t)k * 256 + c], acc);
  }
  const int w = t >> 6, l = t & 63;
#pragma unroll
  for (int o = 32; o > 0; o >>= 1) acc += __shfl_down(acc, o);
  __shared__ float red[4];
  if (l == 0) red[w] = acc;
  __syncthreads();
  if (t == 0) out[c] = red[0] + red[1] + red[2] + red[3] + b2[c];
}

// ---------- W1^T split + FRAGMENT order ----------
__global__ __launch_bounds__(256) void k_wtf(const float* __restrict__ W1,
                                             u16* __restrict__ Wh, u16* __restrict__ Wl) {
  const int bx = blockIdx.x;  // d*512 + cid
  const int d = bx >> 9, cid = bx & 511;
  const int colt = cid >> 6, wcw = (cid >> 5) & 1, ks = (cid >> 2) & 7, j = cid & 3;
  const int t = threadIdx.x, l = t & 63, e0 = (t >> 6) * 2;
  const int n = colt * 128 + wcw * 64 + j * 16 + (l & 15);
  const int k = ks * 32 + (l >> 4) * 8 + e0;
  const float* src = W1 + (size_t)d * 262144;
  const size_t ob = (size_t)bx * 512 + l * 8 + e0;
#pragma unroll
  for (int q = 0; q < 2; ++q) {
    const float v = src[(size_t)(k + q) * 1024 + n];
    const u16 h = bfhi(v);
    Wh[ob + q] = h;
    Wl[ob + q] = bfhi(v - b2f(h));
  }
}

// ---------- codebook split + FRAGMENT order (col = code, k = channel) ----------
__global__ __launch_bounds__(256) void k_csplitf(const float* __restrict__ C,
                                                 u16* __restrict__ Ch, u16* __restrict__ Cl) {
  const int cid = blockIdx.x;  // 512: [colt:3][wcw:1][ks:3][j:2]
  const int colt = cid >> 6, wcw = (cid >> 5) & 1, ks = (cid >> 2) & 7, j = cid & 3;
  const int t = threadIdx.x, l = t & 63, e0 = (t >> 6) * 2;
  const int code = colt * 128 + wcw * 64 + j * 16 + (l & 15);
  const int ch = ks * 32 + (l >> 4) * 8 + e0;
  const size_t ob = (size_t)cid * 512 + l * 8 + e0;
#pragma unroll
  for (int q = 0; q < 2; ++q) {
    const float v = C[(size_t)code * 256 + ch + q];
    const u16 h = bfhi(v);
    Ch[ob + q] = h;
    Cl[ob + q] = bfhi(v - b2f(h));
  }
}

// ---------- numpy-pairwise |c|^2 per code ----------
__device__ __forceinline__ float np_pairwise_sq_256(const float* p) {
  float half[2];
#pragma unroll
  for (int hh = 0; hh < 2; ++hh) {
    float r[8];
#pragma unroll
    for (int j = 0; j < 8; ++j) {
      const float v = p[hh * 128 + j];
      r[j] = __fmul_rn(v, v);
    }
    for (int i = 8; i < 128; i += 8) {
#pragma unroll
      for (int j = 0; j < 8; ++j) {
        const float v = p[hh * 128 + i + j];
        r[j] = __fadd_rn(r[j], __fmul_rn(v, v));
      }
    }
    half[hh] = __fadd_rn(__fadd_rn(__fadd_rn(r[0], r[1]), __fadd_rn(r[2], r[3])),
                         __fadd_rn(__fadd_rn(r[4], r[5]), __fadd_rn(r[6], r[7])));
  }
  return __fadd_rn(half[0], half[1]);
}

__global__ __launch_bounds__(256) void k_c2(const float* __restrict__ cbk, float* __restrict__ c2) {
  const int k = blockIdx.x * 256 + threadIdx.x;
  c2[k] = np_pairwise_sq_256(cbk + (size_t)k * 256);
}

// ---------- index output + quantized gather ----------
__global__ __launch_bounds__(256) void k_idx(const u64* __restrict__ pk, float* __restrict__ outI) {
  const int n = blockIdx.x * 256 + threadIdx.x;
  outI[n] = (float)(unsigned)(pk[n] & 0xffffffffULL);
}

__global__ __launch_bounds__(256) void k_gather(const u64* __restrict__ pk,
                                                const float* __restrict__ cbk,
                                                float* __restrict__ outq) {
  const int t = threadIdx.x;
  const int p0 = blockIdx.x * 64;
  const int b = p0 >> 12, pl = (p0 & 4095) + (t & 63);
  const int cg = t >> 6;
  const int n = p0 + (t & 63);
  const int k = (int)(unsigned)(pk[n] & 0xffffffffULL);
  const float* crow = cbk + (size_t)k * 256 + cg * 64;
  float* ob = outq + (((size_t)(b * 256 + cg * 64)) << 12) + pl;
#pragma unroll 1
  for (int j = 0; j < 16; ++j) {
    const float4 cv = *(const float4*)(crow + j * 4);
    ob[((size_t)(j * 4 + 0)) << 12] = cv.x;
    ob[((size_t)(j * 4 + 1)) << 12] = cv.y;
    ob[((size_t)(j * 4 + 2)) << 12] = cv.z;
    ob[((size_t)(j * 4 + 3)) << 12] = cv.w;
  }
}

extern "C" void kernel_launch(void* const* d_in, const int* in_sizes, int n_in,
                              void* d_out, int out_size, void* d_ws, size_t ws_size,
                              hipStream_t stream) {
  const float* x = (const float*)d_in[0];
  const float* cbk = (const float*)d_in[1];
  const float* Pe[10];
  const float* Pd[10];
  for (int i = 0; i < 10; ++i) Pe[i] = (const float*)d_in[2 + i];
  for (int i = 0; i < 10; ++i) Pd[i] = (const float*)d_in[12 + i];

  float* ws = (float*)d_ws;
  size_t o = 0;
  auto alloc = [&](size_t nf) {
    float* p = ws + o;
    o += (nf + 63) & ~(size_t)63;
    return p;
  };
  float* P1 = alloc(8388608);      // NCHW ping
  u16* Rh = (u16*)alloc(4194304);  // rows hi (also E hi)
  u16* Rl = (u16*)alloc(4194304);  // rows lo (also E lo)
  u16* W1th_e = (u16*)alloc(262144);
  u16* W1tl_e = (u16*)alloc(262144);
  u16* W1th_d = (u16*)alloc(262144);
  u16* W1tl_d = (u16*)alloc(262144);
  u16* W2sh = (u16*)alloc(1048576);
  u16* W2sl = (u16*)alloc(1048576);
  u16* Ch = (u16*)alloc(131072);
  u16* Cl = (u16*)alloc(131072);
  float* C2v = alloc(1024);
  float* GX2 = alloc(8192);
  float* Sv = alloc(8192);
  float* bias2v = alloc(256);
  float* tn = alloc(32768);
  u64* pk = (u64*)alloc(65536);
  const size_t fixedf = o;
  const size_t availf = (ws_size / 4 > fixedf) ? ws_size / 4 - fixedf : 0;
  int chunkB = (int)(availf / 4194304);
  if (chunkB > 8) chunkB = 8;
  if (chunkB < 1) chunkB = 1;
  float* Cv = ws + o;  // conv NCHW fp32, aliases M arena
  u16* Mh = (u16*)(ws + o);
  u16* Ml = (u16*)(ws + o + (size_t)chunkB * 2097152);

  float* outQ = (float*)d_out;
  float* outD = outQ + 8388608;
  float* outI = outD + 8388608;

  auto run_enc = [&](const float* xin, float* xout, u16* Eh, u16* El,
                     const float* const* pp, int d) {
    k_conv<<<2048, 256, 0, stream>>>(xin, pp[0] + (size_t)d * 256 * 49, pp[1] + d * 256, Cv);
    k_lnT<<<1024, 256, 0, stream>>>(Cv, pp[2] + d * 256, pp[3] + d * 256, Rh, Rl, 1);
    k_bias2<<<256, 256, 0, stream>>>(pp[8] + (size_t)d * 262144, pp[7] + d * 1024,
                                     pp[9] + d * 256, bias2v);
    hipMemsetAsync(GX2, 0, 8192 * 4, stream);
    for (int b0 = 0; b0 < 8; b0 += chunkB) {
      const int nb = (8 - b0 < chunkB) ? 8 - b0 : chunkB;
      k_gemm<256, 1, 0, 8><<<dim3(8, nb * 32), 256, 0, stream>>>(
          Rh + (size_t)b0 * 4096 * 256, Rl + (size_t)b0 * 4096 * 256,
          W1th_e + (size_t)d * 262144, W1tl_e + (size_t)d * 262144,
          b0 * 4096, 0, Pe[5] + d * 1024, Mh, Ml, nullptr, nullptr, GX2, nullptr);
      k_grn_scale<<<nb, 256, 0, stream>>>(GX2, pp[6] + d * 1024, Sv, b0);
      k_w2prepf<<<nb * 512, 256, 0, stream>>>(pp[8] + (size_t)d * 262144, Sv, b0, W2sh, W2sl);
      k_gemm<1024, 1, 1, 2><<<dim3(2, nb * 32), 256, 0, stream>>>(
          Mh, Ml, W2sh, W2sl, b0 * 4096, 262144LL, bias2v,
          Eh ? Eh + (size_t)b0 * 4096 * 256 : (u16*)nullptr,
          El ? El + (size_t)b0 * 4096 * 256 : (u16*)nullptr,
          xout, xin, nullptr, nullptr);
    }
  };

  auto run_dec = [&](const float* xin, float* xout, const float* const* pp, int d) {
    k_conv<<<2048, 256, 0, stream>>>(xin, pp[0] + (size_t)d * 256 * 49, pp[1] + d * 256, Cv);
    k_lnT<<<1024, 256, 0, stream>>>(Cv, pp[2] + d * 256, pp[3] + d * 256, Rh, Rl, 0);
    k_bias2<<<256, 256, 0, stream>>>(pp[8] + (size_t)d * 262144, pp[7] + d * 1024,
                                     pp[9] + d * 256, bias2v);
    hipMemsetAsync(GX2, 0, 8192 * 4, stream);
    for (int b0 = 0; b0 < 8; b0 += chunkB) {
      const int nb = (8 - b0 < chunkB) ? 8 - b0 : chunkB;
      k_gemm<256, 0, 0, 8><<<dim3(8, nb * 32), 256, 0, stream>>>(
          Rh + (size_t)b0 * 4096 * 256, nullptr,
          W1th_d + (size_t)d * 262144, nullptr,
          b0 * 4096, 0, Pd[5] + d * 1024, Mh, nullptr, nullptr, nullptr, GX2, nullptr);
      k_grn_scale<<<nb, 256, 0, stream>>>(GX2, pp[6] + d * 1024, Sv, b0);
      k_w2prepf<<<nb * 512, 256, 0, stream>>>(pp[8] + (size_t)d * 262144, Sv, b0, W2sh, W2sl);
      k_gemm<1024, 0, 1, 2><<<dim3(2, nb * 32), 256, 0, stream>>>(
          Mh, nullptr, W2sh, nullptr, b0 * 4096, 262144LL, bias2v,
          nullptr, nullptr, xout, xin, nullptr, nullptr);
    }
  };

  // prep (fragment-ordered B operands)
  k_wtf<<<1024, 256, 0, stream>>>(Pe[4], W1th_e, W1tl_e);
  k_wtf<<<1024, 256, 0, stream>>>(Pd[4], W1th_d, W1tl_d);
  k_csplitf<<<512, 256, 0, stream>>>(cbk, Ch, Cl);
  k_c2<<<4, 256, 0, stream>>>(cbk, C2v);

  // encoder (split-bf16, fused 3-term)
  run_enc(x, P1, nullptr, nullptr, Pe, 0);
  run_enc(P1, nullptr, Rh, Rl, Pe, 1);  // E -> Rh/Rl, no NCHW out

  // VQ
  k_rownorm<<<512, 256, 0, stream>>>(Rh, Rl, tn);
  hipMemsetAsync(pk, 0xFF, 32768 * 8, stream);
  k_gemm<256, 1, 2, 8><<<dim3(8, 256), 256, 0, stream>>>(Rh, Rl, Ch, Cl, 0, 0,
                                                         C2v, nullptr, nullptr, nullptr,
                                                         tn, nullptr, pk);
  k_idx<<<128, 256, 0, stream>>>(pk, outI);
  k_gather<<<512, 256, 0, stream>>>(pk, cbk, outQ);

  // decoder (plain bf16)
  run_dec(outQ, P1, Pd, 0);
  run_dec(P1, outD, Pd, 1);
}